// Round 1
// baseline (1134.642 us; speedup 1.0000x reference)
//
#include <hip/hip_runtime.h>

// NonLocalBlock: B=8, L=2048, C=512, CI=256, fp32.
//   xp = X@Wx+bx [B,L,CI]; yp = X@Wy+by; op = X@Wo+bo [B,L,C]
//   S[b,l,m] = xp[b,l,:].yp[b,m,:];  attn = softmax over b (elementwise in (l,m)!)
//   out = X + attn @ op
// Round 0: all-fp32 tiled vector GEMMs (no fp32 MFMA on CDNA4). Correctness baseline.

#define NB 8
#define NL 2048
#define NC 512
#define NCI 256

constexpr int BM = 64, BN = 64, BK = 16;

// 256 threads (16x16), each computes a 4x4 micro-tile of a 64x64 block.
// A is [M x K] row-major (lda). B is [K x N] row-major (ldb) unless TRANSB,
// in which case B is [N x K] row-major and we compute A @ B^T.
template <bool TRANSB>
__device__ __forceinline__ void gemm_tile_compute(
    const float* __restrict__ A, const float* __restrict__ B,
    int K, int lda, int ldb, int block_row, int block_col, float acc[4][4])
{
    __shared__ __align__(16) float As[BK][BM + 4];
    __shared__ __align__(16) float Bs[BK][BN + 4];
    const int tid = threadIdx.x;
    const int tx = tid & 15;
    const int ty = tid >> 4;

    for (int k0 = 0; k0 < K; k0 += BK) {
        // A tile: 64 rows x 16 k. 16 consecutive threads read one row's 16 k's.
#pragma unroll
        for (int i = 0; i < 4; ++i) {
            int t = tid + i * 256;
            int r = t >> 4;
            int kk = t & 15;
            As[kk][r] = A[(size_t)(block_row + r) * lda + (k0 + kk)];
        }
        if (!TRANSB) {
            // B tile: 16 k x 64 cols, fully coalesced over cols.
#pragma unroll
            for (int i = 0; i < 4; ++i) {
                int t = tid + i * 256;
                int kk = t >> 6;
                int c = t & 63;
                Bs[kk][c] = B[(size_t)(k0 + kk) * ldb + (block_col + c)];
            }
        } else {
            // B^T tile: 64 rows x 16 k, same pattern as A.
#pragma unroll
            for (int i = 0; i < 4; ++i) {
                int t = tid + i * 256;
                int c = t >> 4;
                int kk = t & 15;
                Bs[kk][c] = B[(size_t)(block_col + c) * ldb + (k0 + kk)];
            }
        }
        __syncthreads();
#pragma unroll
        for (int kk = 0; kk < BK; ++kk) {
            float4 a4 = *reinterpret_cast<const float4*>(&As[kk][ty * 4]);
            float4 b4 = *reinterpret_cast<const float4*>(&Bs[kk][tx * 4]);
            float a[4] = {a4.x, a4.y, a4.z, a4.w};
            float b[4] = {b4.x, b4.y, b4.z, b4.w};
#pragma unroll
            for (int i = 0; i < 4; ++i)
#pragma unroll
                for (int j = 0; j < 4; ++j)
                    acc[i][j] = fmaf(a[i], b[j], acc[i][j]);
        }
        __syncthreads();
    }
}

// Stage 1: fused projection GEMM. X[16384x512] @ (Wx|Wy|Wo)[512x1024] + bias.
// Each 64-col block falls entirely inside one of the three weight segments.
__global__ __launch_bounds__(256) void proj_kernel(
    const float* __restrict__ X,
    const float* __restrict__ Wx, const float* __restrict__ bx,
    const float* __restrict__ Wy, const float* __restrict__ by,
    const float* __restrict__ Wo, const float* __restrict__ bo,
    float* __restrict__ xp, float* __restrict__ yp, float* __restrict__ op)
{
    const int bcol = blockIdx.y * BN;
    const float* W; const float* bias; float* Out; int ldo; int coloff;
    if (bcol < NCI)          { W = Wx; bias = bx; Out = xp; ldo = NCI; coloff = bcol; }
    else if (bcol < 2 * NCI) { W = Wy; bias = by; Out = yp; ldo = NCI; coloff = bcol - NCI; }
    else                     { W = Wo; bias = bo; Out = op; ldo = NC;  coloff = bcol - 2 * NCI; }

    float acc[4][4] = {};
    gemm_tile_compute<false>(X, W, NC, NC, ldo, blockIdx.x * BM, coloff, acc);

    const int tx = threadIdx.x & 15;
    const int ty = threadIdx.x >> 4;
    const int row0 = blockIdx.x * BM + ty * 4;
    const int col0 = coloff + tx * 4;
#pragma unroll
    for (int i = 0; i < 4; ++i) {
        float4 v;
        v.x = acc[i][0] + bias[col0 + 0];
        v.y = acc[i][1] + bias[col0 + 1];
        v.z = acc[i][2] + bias[col0 + 2];
        v.w = acc[i][3] + bias[col0 + 3];
        *reinterpret_cast<float4*>(&Out[(size_t)(row0 + i) * ldo + col0]) = v;
    }
}

// Stage 2: S[b] = xp[b] @ yp[b]^T   (2048x2048, K=256)
__global__ __launch_bounds__(256) void score_kernel(
    const float* __restrict__ xp, const float* __restrict__ yp, float* __restrict__ S)
{
    const int b = blockIdx.z;
    const float* A  = xp + (size_t)b * NL * NCI;
    const float* Bm = yp + (size_t)b * NL * NCI;
    float* Sb       = S  + (size_t)b * NL * NL;

    float acc[4][4] = {};
    gemm_tile_compute<true>(A, Bm, NCI, NCI, NCI, blockIdx.x * BM, blockIdx.y * BN, acc);

    const int tx = threadIdx.x & 15;
    const int ty = threadIdx.x >> 4;
    const int row0 = blockIdx.x * BM + ty * 4;
    const int col0 = blockIdx.y * BN + tx * 4;
#pragma unroll
    for (int i = 0; i < 4; ++i) {
        float4 v = {acc[i][0], acc[i][1], acc[i][2], acc[i][3]};
        *reinterpret_cast<float4*>(&Sb[(size_t)(row0 + i) * NL + col0]) = v;
    }
}

// Stage 3: softmax over the batch axis, in place. One thread per (l,m).
__global__ __launch_bounds__(256) void softmax_kernel(float* __restrict__ S)
{
    const size_t idx = (size_t)blockIdx.x * 256 + threadIdx.x;   // over L*L
    const size_t stride = (size_t)NL * NL;
    float v[NB];
    float mx = -1e30f;
#pragma unroll
    for (int b = 0; b < NB; ++b) {
        v[b] = S[idx + b * stride];
        mx = fmaxf(mx, v[b]);
    }
    float sum = 0.f;
#pragma unroll
    for (int b = 0; b < NB; ++b) {
        v[b] = expf(v[b] - mx);
        sum += v[b];
    }
    const float inv = 1.f / sum;
#pragma unroll
    for (int b = 0; b < NB; ++b)
        S[idx + b * stride] = v[b] * inv;
}

// Stage 4: out[b] = X[b] + attn[b] @ op[b]   (2048x512, K=2048)
__global__ __launch_bounds__(256) void out_kernel(
    const float* __restrict__ S, const float* __restrict__ op,
    const float* __restrict__ X, float* __restrict__ Out)
{
    const int b = blockIdx.z;
    const float* A  = S  + (size_t)b * NL * NL;
    const float* Bm = op + (size_t)b * NL * NC;

    float acc[4][4] = {};
    gemm_tile_compute<false>(A, Bm, NL, NL, NC, blockIdx.x * BM, blockIdx.y * BN, acc);

    const int tx = threadIdx.x & 15;
    const int ty = threadIdx.x >> 4;
    const int row0 = blockIdx.x * BM + ty * 4;
    const int col0 = blockIdx.y * BN + tx * 4;
    const size_t base = (size_t)b * NL * NC;
#pragma unroll
    for (int i = 0; i < 4; ++i) {
        const size_t o = base + (size_t)(row0 + i) * NC + col0;
        float4 xin = *reinterpret_cast<const float4*>(&X[o]);
        float4 v;
        v.x = xin.x + acc[i][0];
        v.y = xin.y + acc[i][1];
        v.z = xin.z + acc[i][2];
        v.w = xin.w + acc[i][3];
        *reinterpret_cast<float4*>(&Out[o]) = v;
    }
}

extern "C" void kernel_launch(void* const* d_in, const int* in_sizes, int n_in,
                              void* d_out, int out_size, void* d_ws, size_t ws_size,
                              hipStream_t stream)
{
    const float* X  = (const float*)d_in[0];
    const float* Wx = (const float*)d_in[1];
    const float* bx = (const float*)d_in[2];
    const float* Wy = (const float*)d_in[3];
    const float* by = (const float*)d_in[4];
    const float* Wo = (const float*)d_in[5];
    const float* bo = (const float*)d_in[6];
    float* out = (float*)d_out;

    // Workspace layout (floats): xp | yp | op | S   (~192 MiB total)
    float* ws = (float*)d_ws;
    float* xp = ws;
    float* yp = xp + (size_t)NB * NL * NCI;
    float* op = yp + (size_t)NB * NL * NCI;
    float* S  = op + (size_t)NB * NL * NC;

    dim3 blk(256);

    // Stage 1: projections
    proj_kernel<<<dim3((NB * NL) / BM, (2 * NCI + NC) / BN), blk, 0, stream>>>(
        X, Wx, bx, Wy, by, Wo, bo, xp, yp, op);

    // Stage 2: scores per batch
    score_kernel<<<dim3(NL / BM, NL / BN, NB), blk, 0, stream>>>(xp, yp, S);

    // Stage 3: softmax over batch axis (in place)
    softmax_kernel<<<dim3(((size_t)NL * NL) / 256), blk, 0, stream>>>(S);

    // Stage 4: out = X + attn @ op
    out_kernel<<<dim3(NL / BM, NC / BN, NB), blk, 0, stream>>>(S, op, X, out);
}

// Round 2
// 322.314 us; speedup vs baseline: 3.5203x; 3.5203x over previous
//
#include <hip/hip_runtime.h>

// NonLocalBlock B=8, L=2048, C=512, CI=256 (fp32 in/out).
// Round 2: MFMA everywhere.
//   - score-critical chain (xp, yp, scores) in SPLIT bf16 (hi+lo, 3 MFMAs) ~ fp32 accurate
//   - op projection & out GEMM in plain bf16 (error budget allows)
//   - softmax over batch axis in fp32, writes attn as bf16 packed into the low
//     half of each fp32 slot (no extra buffer, race-free)
// GEMM structure: 128x128 block tile, BK=32, 4 waves (each 64x64 = 4x4 MFMAs of
// 16x16x32), global_load_lds width=16 staging (m97-verified pattern).

#define NB 8
#define NL 2048
#define NC 512
#define NCI 256

using bf16x8 = __attribute__((ext_vector_type(8))) short;
using f32x4  = __attribute__((ext_vector_type(4))) float;
typedef unsigned short u16;

__device__ __forceinline__ unsigned bf16rn(float f) {
    unsigned u = __float_as_uint(f);
    return (u + 0x7FFFu + ((u >> 16) & 1u)) >> 16;   // bf16 bits, round-nearest-even
}
__device__ __forceinline__ void split2(float x, u16& h, u16& l) {
    unsigned hb = bf16rn(x);
    float fh = __uint_as_float(hb << 16);
    h = (u16)hb;
    l = (u16)bf16rn(x - fh);
}
__device__ __forceinline__ void gload16(const void* g, void* l) {
    __builtin_amdgcn_global_load_lds((__attribute__((address_space(1))) void*)g,
                                     (__attribute__((address_space(3))) void*)l,
                                     16, 0, 0);
}

// ---- converts -------------------------------------------------------------
__global__ __launch_bounds__(256) void cvt_x_kernel(const float* __restrict__ X,
                                                    u16* __restrict__ Xh,
                                                    u16* __restrict__ Xl)
{
    size_t i = (size_t)blockIdx.x * 256 + threadIdx.x;   // float4 index
    float4 v = ((const float4*)X)[i];
    u16 h0, h1, h2, h3, l0, l1, l2, l3;
    split2(v.x, h0, l0); split2(v.y, h1, l1);
    split2(v.z, h2, l2); split2(v.w, h3, l3);
    ushort4 H; H.x = h0; H.y = h1; H.z = h2; H.w = h3;
    ushort4 L; L.x = l0; L.y = l1; L.z = l2; L.w = l3;
    ((ushort4*)Xh)[i] = H;
    ((ushort4*)Xl)[i] = L;
}

// Transpose + split weights: WxT/WyT [CI][C] hi+lo, WoT [C][C] hi only.
__global__ __launch_bounds__(256) void cvt_w_kernel(
    const float* __restrict__ Wx, const float* __restrict__ Wy, const float* __restrict__ Wo,
    u16* __restrict__ WxTh, u16* __restrict__ WxTl,
    u16* __restrict__ WyTh, u16* __restrict__ WyTl, u16* __restrict__ WoTh)
{
    const int bid = blockIdx.x, t = threadIdx.x;
#pragma unroll
    for (int kk = 0; kk < 2; ++kk) {
        const int k = t + kk * 256;
        if (bid < 256) {
            u16 h, l; split2(Wx[(size_t)k * NCI + bid], h, l);
            WxTh[(size_t)bid * NC + k] = h; WxTl[(size_t)bid * NC + k] = l;
        } else if (bid < 512) {
            const int n = bid - 256;
            u16 h, l; split2(Wy[(size_t)k * NCI + n], h, l);
            WyTh[(size_t)n * NC + k] = h; WyTl[(size_t)n * NC + k] = l;
        } else {
            const int n = bid - 512;
            WoTh[(size_t)n * NC + k] = (u16)bf16rn(Wo[(size_t)k * NC + n]);
        }
    }
}

// ---- projections ----------------------------------------------------------
// grid (128, 8): x = 128-row tile over B*L; y: 0-1 xp (split), 2-3 yp (split),
// 4-7 op (plain, written transposed to opT[b][c][m]).
__global__ __launch_bounds__(256) void proj_kernel(
    const u16* __restrict__ Xh, const u16* __restrict__ Xl,
    const u16* __restrict__ WxTh, const u16* __restrict__ WxTl,
    const u16* __restrict__ WyTh, const u16* __restrict__ WyTl,
    const u16* __restrict__ WoTh,
    const float* __restrict__ bx, const float* __restrict__ by, const float* __restrict__ bo,
    u16* __restrict__ xph, u16* __restrict__ xpl,
    u16* __restrict__ yph, u16* __restrict__ ypl,
    u16* __restrict__ opT)
{
    __shared__ __align__(16) u16 SM[17408];   // stage: 4x(128x32)=32KB; Ts reuse: 128x136
    u16* As  = SM;
    u16* Als = SM + 4096;
    u16* Bs  = SM + 8192;
    u16* Bls = SM + 12288;

    const int tid = threadIdx.x;
    const int w = tid >> 6, lane = tid & 63;
    const int row0 = blockIdx.x * 128;
    const int cb = blockIdx.y;

    const u16 *Wh, *Wl = nullptr; const float* bias;
    int n0, path;
    if (cb < 2)      { path = 0; n0 = cb * 128;       Wh = WxTh; Wl = WxTl; bias = bx; }
    else if (cb < 4) { path = 1; n0 = (cb - 2) * 128; Wh = WyTh; Wl = WyTl; bias = by; }
    else             { path = 2; n0 = (cb - 4) * 128; Wh = WoTh;            bias = bo; }
    const bool split = (path != 2);

    f32x4 acc[4][4] = {};
    const int wm = (w & 1) * 64, wn = (w >> 1) * 64;
    const int fr = lane & 15, fq = lane >> 4;
    const int sr = lane >> 2, sc = (lane & 3) * 8;

    for (int k0 = 0; k0 < NC; k0 += 32) {
#pragma unroll
        for (int t = 0; t < 2; ++t) {
            const int rb = (w * 2 + t) * 16;
            const size_t ar = (size_t)(row0 + rb + sr) * NC + k0 + sc;
            const size_t br = (size_t)(n0 + rb + sr) * NC + k0 + sc;
            gload16(Xh + ar, (char*)As + rb * 64);
            gload16(Wh + br, (char*)Bs + rb * 64);
            if (split) {
                gload16(Xl + ar, (char*)Als + rb * 64);
                gload16(Wl + br, (char*)Bls + rb * 64);
            }
        }
        __syncthreads();
        bf16x8 ah[4], bh[4], al[4], bl[4];
#pragma unroll
        for (int mi = 0; mi < 4; ++mi)
            ah[mi] = *(const bf16x8*)&As[(wm + mi * 16 + fr) * 32 + fq * 8];
#pragma unroll
        for (int ni = 0; ni < 4; ++ni)
            bh[ni] = *(const bf16x8*)&Bs[(wn + ni * 16 + fr) * 32 + fq * 8];
        if (split) {
#pragma unroll
            for (int mi = 0; mi < 4; ++mi)
                al[mi] = *(const bf16x8*)&Als[(wm + mi * 16 + fr) * 32 + fq * 8];
#pragma unroll
            for (int ni = 0; ni < 4; ++ni)
                bl[ni] = *(const bf16x8*)&Bls[(wn + ni * 16 + fr) * 32 + fq * 8];
        }
#pragma unroll
        for (int mi = 0; mi < 4; ++mi)
#pragma unroll
            for (int ni = 0; ni < 4; ++ni) {
                acc[mi][ni] = __builtin_amdgcn_mfma_f32_16x16x32_bf16(ah[mi], bh[ni], acc[mi][ni], 0, 0, 0);
                if (split) {
                    acc[mi][ni] = __builtin_amdgcn_mfma_f32_16x16x32_bf16(ah[mi], bl[ni], acc[mi][ni], 0, 0, 0);
                    acc[mi][ni] = __builtin_amdgcn_mfma_f32_16x16x32_bf16(al[mi], bh[ni], acc[mi][ni], 0, 0, 0);
                }
            }
        __syncthreads();
    }

    if (split) {
        u16* OH = (path == 0) ? xph : yph;
        u16* OL = (path == 0) ? xpl : ypl;
#pragma unroll
        for (int mi = 0; mi < 4; ++mi) {
            const int grow = row0 + wm + mi * 16 + fq * 4;
#pragma unroll
            for (int ni = 0; ni < 4; ++ni) {
                const int gcol = n0 + wn + ni * 16 + fr;
                const float bv = bias[gcol];
#pragma unroll
                for (int r = 0; r < 4; ++r) {
                    u16 h, l; split2(acc[mi][ni][r] + bv, h, l);
                    const size_t off = (size_t)(grow + r) * NCI + gcol;
                    OH[off] = h; OL[off] = l;
                }
            }
        }
    } else {
        u16* Ts = SM;   // 128 x 136 bf16 transpose staging (stride 272B, 16B-aligned)
#pragma unroll
        for (int mi = 0; mi < 4; ++mi) {
            const int mb = wm + mi * 16 + fq * 4;
#pragma unroll
            for (int ni = 0; ni < 4; ++ni) {
                const int nl_ = wn + ni * 16 + fr;
                const float bv = bias[n0 + nl_];
#pragma unroll
                for (int r = 0; r < 4; ++r)
                    Ts[nl_ * 136 + mb + r] = (u16)bf16rn(acc[mi][ni][r] + bv);
            }
        }
        __syncthreads();
        const int b = row0 >> 11, m0 = row0 & 2047;
        u16* dst = opT + (size_t)b * NC * NL + (size_t)n0 * NL + m0;
        for (int i = tid; i < 128 * 16; i += 256) {
            const int c = i >> 4, ch = i & 15;
            uint4 v = *(const uint4*)&Ts[c * 136 + ch * 8];
            *(uint4*)&dst[(size_t)c * NL + ch * 8] = v;
        }
    }
}

// ---- scores: S[b] = xp[b] @ yp[b]^T, split bf16 (3 MFMAs) ------------------
__global__ __launch_bounds__(256) void score_kernel(
    const u16* __restrict__ xph, const u16* __restrict__ xpl,
    const u16* __restrict__ yph, const u16* __restrict__ ypl,
    float* __restrict__ S)
{
    __shared__ __align__(16) u16 As[4096], Als[4096], Bs[4096], Bls[4096];
    const int tid = threadIdx.x;
    const int w = tid >> 6, lane = tid & 63;
    const int b = blockIdx.z;
    const int row0 = blockIdx.x * 128, col0 = blockIdx.y * 128;
    const size_t ab = (size_t)b * NL * NCI;
    const u16* Ah = xph + ab; const u16* Al = xpl + ab;
    const u16* Bh = yph + ab; const u16* Bl = ypl + ab;

    f32x4 acc[4][4] = {};
    const int wm = (w & 1) * 64, wn = (w >> 1) * 64;
    const int fr = lane & 15, fq = lane >> 4;
    const int sr = lane >> 2, sc = (lane & 3) * 8;

    for (int k0 = 0; k0 < NCI; k0 += 32) {
#pragma unroll
        for (int t = 0; t < 2; ++t) {
            const int rb = (w * 2 + t) * 16;
            const size_t ar = (size_t)(row0 + rb + sr) * NCI + k0 + sc;
            const size_t br = (size_t)(col0 + rb + sr) * NCI + k0 + sc;
            gload16(Ah + ar, (char*)As + rb * 64);
            gload16(Al + ar, (char*)Als + rb * 64);
            gload16(Bh + br, (char*)Bs + rb * 64);
            gload16(Bl + br, (char*)Bls + rb * 64);
        }
        __syncthreads();
        bf16x8 ah[4], al[4], bh[4], bl[4];
#pragma unroll
        for (int mi = 0; mi < 4; ++mi) {
            ah[mi] = *(const bf16x8*)&As[(wm + mi * 16 + fr) * 32 + fq * 8];
            al[mi] = *(const bf16x8*)&Als[(wm + mi * 16 + fr) * 32 + fq * 8];
        }
#pragma unroll
        for (int ni = 0; ni < 4; ++ni) {
            bh[ni] = *(const bf16x8*)&Bs[(wn + ni * 16 + fr) * 32 + fq * 8];
            bl[ni] = *(const bf16x8*)&Bls[(wn + ni * 16 + fr) * 32 + fq * 8];
        }
#pragma unroll
        for (int mi = 0; mi < 4; ++mi)
#pragma unroll
            for (int ni = 0; ni < 4; ++ni) {
                acc[mi][ni] = __builtin_amdgcn_mfma_f32_16x16x32_bf16(ah[mi], bh[ni], acc[mi][ni], 0, 0, 0);
                acc[mi][ni] = __builtin_amdgcn_mfma_f32_16x16x32_bf16(ah[mi], bl[ni], acc[mi][ni], 0, 0, 0);
                acc[mi][ni] = __builtin_amdgcn_mfma_f32_16x16x32_bf16(al[mi], bh[ni], acc[mi][ni], 0, 0, 0);
            }
        __syncthreads();
    }
    float* Sb = S + (size_t)b * NL * NL;
#pragma unroll
    for (int mi = 0; mi < 4; ++mi) {
        const int gr = row0 + wm + mi * 16 + fq * 4;
#pragma unroll
        for (int ni = 0; ni < 4; ++ni) {
            const int gc = col0 + wn + ni * 16 + fr;
#pragma unroll
            for (int r = 0; r < 4; ++r)
                Sb[(size_t)(gr + r) * NL + gc] = acc[mi][ni][r];
        }
    }
}

// ---- softmax over batch axis; writes attn bf16 into low half of each slot --
__global__ __launch_bounds__(256) void softmax_kernel(float* __restrict__ S)
{
    const size_t i = (size_t)blockIdx.x * 256 + threadIdx.x;   // float4 index over L*L/4
    const size_t st = (size_t)NL * NL / 4;
    float4* S4 = (float4*)S;
    float4 v[NB];
#pragma unroll
    for (int b = 0; b < NB; ++b) v[b] = S4[i + b * st];
    float4 mx = v[0];
#pragma unroll
    for (int b = 1; b < NB; ++b) {
        mx.x = fmaxf(mx.x, v[b].x); mx.y = fmaxf(mx.y, v[b].y);
        mx.z = fmaxf(mx.z, v[b].z); mx.w = fmaxf(mx.w, v[b].w);
    }
    float4 s = {0.f, 0.f, 0.f, 0.f};
#pragma unroll
    for (int b = 0; b < NB; ++b) {
        v[b].x = __expf(v[b].x - mx.x); s.x += v[b].x;
        v[b].y = __expf(v[b].y - mx.y); s.y += v[b].y;
        v[b].z = __expf(v[b].z - mx.z); s.z += v[b].z;
        v[b].w = __expf(v[b].w - mx.w); s.w += v[b].w;
    }
    float4 inv; inv.x = 1.f / s.x; inv.y = 1.f / s.y; inv.z = 1.f / s.z; inv.w = 1.f / s.w;
#pragma unroll
    for (int b = 0; b < NB; ++b) {
        float4 o;
        o.x = __uint_as_float(bf16rn(v[b].x * inv.x));
        o.y = __uint_as_float(bf16rn(v[b].y * inv.y));
        o.z = __uint_as_float(bf16rn(v[b].z * inv.z));
        o.w = __uint_as_float(bf16rn(v[b].w * inv.w));
        S4[i + b * st] = o;
    }
}

// ---- out: out[b] = X[b] + attn[b] @ op[b], plain bf16 MFMA -----------------
__global__ __launch_bounds__(256) void out_kernel(
    const float* __restrict__ Sa, const u16* __restrict__ opT,
    const float* __restrict__ X, float* __restrict__ Out)
{
    __shared__ __align__(16) u16 As[4096], Bs[4096];
    const int tid = threadIdx.x;
    const int w = tid >> 6, lane = tid & 63;
    const int b = blockIdx.z;
    const int row0 = blockIdx.x * 128, col0 = blockIdx.y * 128;
    const unsigned* Sb = (const unsigned*)(Sa + (size_t)b * NL * NL);
    const u16* Bsrc = opT + (size_t)b * NC * NL;

    f32x4 acc[4][4] = {};
    const int wm = (w & 1) * 64, wn = (w >> 1) * 64;
    const int fr = lane & 15, fq = lane >> 4;
    const int sr = lane >> 2, sc = (lane & 3) * 8;

    for (int k0 = 0; k0 < NL; k0 += 32) {
        // A stage: pack bf16 attn from low halves of fp32 slots (2x v_perm per 4)
#pragma unroll
        for (int i = 0; i < 4; ++i) {
            const int chunk = tid + i * 256;
            const int r = chunk >> 3, c4 = chunk & 7;
            uint4 q = *(const uint4*)&Sb[(size_t)(row0 + r) * NL + k0 + c4 * 4];
            uint2 p;
            p.x = __builtin_amdgcn_perm(q.y, q.x, 0x05040100u);
            p.y = __builtin_amdgcn_perm(q.w, q.z, 0x05040100u);
            *(uint2*)((char*)As + r * 64 + c4 * 8) = p;
        }
#pragma unroll
        for (int t = 0; t < 2; ++t) {
            const int rb = (w * 2 + t) * 16;
            gload16(Bsrc + (size_t)(col0 + rb + sr) * NL + k0 + sc, (char*)Bs + rb * 64);
        }
        __syncthreads();
        bf16x8 af[4], bfr[4];
#pragma unroll
        for (int mi = 0; mi < 4; ++mi)
            af[mi] = *(const bf16x8*)&As[(wm + mi * 16 + fr) * 32 + fq * 8];
#pragma unroll
        for (int ni = 0; ni < 4; ++ni)
            bfr[ni] = *(const bf16x8*)&Bs[(wn + ni * 16 + fr) * 32 + fq * 8];
#pragma unroll
        for (int mi = 0; mi < 4; ++mi)
#pragma unroll
            for (int ni = 0; ni < 4; ++ni)
                acc[mi][ni] = __builtin_amdgcn_mfma_f32_16x16x32_bf16(af[mi], bfr[ni], acc[mi][ni], 0, 0, 0);
        __syncthreads();
    }
    const size_t ob = (size_t)b * NL * NC;
#pragma unroll
    for (int mi = 0; mi < 4; ++mi) {
        const int gr = row0 + wm + mi * 16 + fq * 4;
#pragma unroll
        for (int ni = 0; ni < 4; ++ni) {
            const int gc = col0 + wn + ni * 16 + fr;
#pragma unroll
            for (int r = 0; r < 4; ++r) {
                const size_t o = ob + (size_t)(gr + r) * NC + gc;
                Out[o] = X[o] + acc[mi][ni][r];
            }
        }
    }
}

extern "C" void kernel_launch(void* const* d_in, const int* in_sizes, int n_in,
                              void* d_out, int out_size, void* d_ws, size_t ws_size,
                              hipStream_t stream)
{
    const float* X  = (const float*)d_in[0];
    const float* Wx = (const float*)d_in[1];
    const float* bx = (const float*)d_in[2];
    const float* Wy = (const float*)d_in[3];
    const float* by = (const float*)d_in[4];
    const float* Wo = (const float*)d_in[5];
    const float* bo = (const float*)d_in[6];
    float* out = (float*)d_out;

    // Workspace (186.1 MB; round-0 proved >=201 MB usable):
    //   S fp32 [0, 128MB) — Xh/Xl (bf16, 16MB each) live in S's region, dead before
    //   score_kernel writes S (kernels are stream-ordered).
    char* ws = (char*)d_ws;
    float* S  = (float*)ws;
    u16* Xh   = (u16*)ws;
    u16* Xl   = (u16*)(ws + 16777216);
    char* p = ws + 134217728;
    u16* xph = (u16*)p;  p += 8388608;
    u16* xpl = (u16*)p;  p += 8388608;
    u16* yph = (u16*)p;  p += 8388608;
    u16* ypl = (u16*)p;  p += 8388608;
    u16* opT = (u16*)p;  p += 16777216;
    u16* WxTh = (u16*)p; p += 262144;
    u16* WxTl = (u16*)p; p += 262144;
    u16* WyTh = (u16*)p; p += 262144;
    u16* WyTl = (u16*)p; p += 262144;
    u16* WoTh = (u16*)p; p += 524288;

    cvt_x_kernel<<<8192, 256, 0, stream>>>(X, Xh, Xl);
    cvt_w_kernel<<<1024, 256, 0, stream>>>(Wx, Wy, Wo, WxTh, WxTl, WyTh, WyTl, WoTh);
    proj_kernel<<<dim3(128, 8), 256, 0, stream>>>(Xh, Xl, WxTh, WxTl, WyTh, WyTl, WoTh,
                                                  bx, by, bo, xph, xpl, yph, ypl, opT);
    score_kernel<<<dim3(16, 16, NB), 256, 0, stream>>>(xph, xpl, yph, ypl, S);
    softmax_kernel<<<4096, 256, 0, stream>>>(S);
    out_kernel<<<dim3(16, 4, NB), 256, 0, stream>>>(S, opT, X, out);
}

// Round 3
// 280.680 us; speedup vs baseline: 4.0425x; 1.1483x over previous
//
#include <hip/hip_runtime.h>
#include <hip/hip_fp16.h>

// NonLocalBlock B=8, L=2048, C=512, CI=256 (fp32 in/out).
// Round 3: 16-bit score tensor both directions.
//   - xp/yp/scores chain in SPLIT bf16 (hi+lo, 3 MFMAs) ~ fp32 accurate
//   - scores stored as FP16 (64 MB; |s| <= ~121 fits, rel err 2^-11)
//   - softmax over batch axis: exact max-subtract in fp32, rewrites compact
//     bf16 attn IN PLACE into the same u16 slots (race-free)
//   - out GEMM: A = compact bf16 attn via global_load_lds (no perm packing)
// GEMM structure: 128x128 tile, BK=32, 4 waves, global_load_lds width=16.

#define NB 8
#define NL 2048
#define NC 512
#define NCI 256

using bf16x8 = __attribute__((ext_vector_type(8))) short;
using f32x4  = __attribute__((ext_vector_type(4))) float;
using f16x8  = __attribute__((ext_vector_type(8))) _Float16;
typedef unsigned short u16;

__device__ __forceinline__ unsigned bf16rn(float f) {
    unsigned u = __float_as_uint(f);
    return (u + 0x7FFFu + ((u >> 16) & 1u)) >> 16;   // bf16 bits, round-nearest-even
}
__device__ __forceinline__ void split2(float x, u16& h, u16& l) {
    unsigned hb = bf16rn(x);
    float fh = __uint_as_float(hb << 16);
    h = (u16)hb;
    l = (u16)bf16rn(x - fh);
}
__device__ __forceinline__ void gload16(const void* g, void* l) {
    __builtin_amdgcn_global_load_lds((__attribute__((address_space(1))) void*)g,
                                     (__attribute__((address_space(3))) void*)l,
                                     16, 0, 0);
}

// ---- converts -------------------------------------------------------------
__global__ __launch_bounds__(256) void cvt_x_kernel(const float* __restrict__ X,
                                                    u16* __restrict__ Xh,
                                                    u16* __restrict__ Xl)
{
    size_t i = (size_t)blockIdx.x * 256 + threadIdx.x;   // float4 index
    float4 v = ((const float4*)X)[i];
    u16 h0, h1, h2, h3, l0, l1, l2, l3;
    split2(v.x, h0, l0); split2(v.y, h1, l1);
    split2(v.z, h2, l2); split2(v.w, h3, l3);
    ushort4 H; H.x = h0; H.y = h1; H.z = h2; H.w = h3;
    ushort4 L; L.x = l0; L.y = l1; L.z = l2; L.w = l3;
    ((ushort4*)Xh)[i] = H;
    ((ushort4*)Xl)[i] = L;
}

// Transpose + split weights: WxT/WyT [CI][C] hi+lo, WoT [C][C] hi only.
__global__ __launch_bounds__(256) void cvt_w_kernel(
    const float* __restrict__ Wx, const float* __restrict__ Wy, const float* __restrict__ Wo,
    u16* __restrict__ WxTh, u16* __restrict__ WxTl,
    u16* __restrict__ WyTh, u16* __restrict__ WyTl, u16* __restrict__ WoTh)
{
    const int bid = blockIdx.x, t = threadIdx.x;
#pragma unroll
    for (int kk = 0; kk < 2; ++kk) {
        const int k = t + kk * 256;
        if (bid < 256) {
            u16 h, l; split2(Wx[(size_t)k * NCI + bid], h, l);
            WxTh[(size_t)bid * NC + k] = h; WxTl[(size_t)bid * NC + k] = l;
        } else if (bid < 512) {
            const int n = bid - 256;
            u16 h, l; split2(Wy[(size_t)k * NCI + n], h, l);
            WyTh[(size_t)n * NC + k] = h; WyTl[(size_t)n * NC + k] = l;
        } else {
            const int n = bid - 512;
            WoTh[(size_t)n * NC + k] = (u16)bf16rn(Wo[(size_t)k * NC + n]);
        }
    }
}

// ---- projections ----------------------------------------------------------
// grid (128, 8): x = 128-row tile over B*L; y: 0-1 xp (split), 2-3 yp (split),
// 4-7 op (plain, written transposed to opT[b][c][m]).
__global__ __launch_bounds__(256) void proj_kernel(
    const u16* __restrict__ Xh, const u16* __restrict__ Xl,
    const u16* __restrict__ WxTh, const u16* __restrict__ WxTl,
    const u16* __restrict__ WyTh, const u16* __restrict__ WyTl,
    const u16* __restrict__ WoTh,
    const float* __restrict__ bx, const float* __restrict__ by, const float* __restrict__ bo,
    u16* __restrict__ xph, u16* __restrict__ xpl,
    u16* __restrict__ yph, u16* __restrict__ ypl,
    u16* __restrict__ opT)
{
    __shared__ __align__(16) u16 SM[17408];   // stage: 4x(128x32)=32KB; Ts reuse: 128x136
    u16* As  = SM;
    u16* Als = SM + 4096;
    u16* Bs  = SM + 8192;
    u16* Bls = SM + 12288;

    const int tid = threadIdx.x;
    const int w = tid >> 6, lane = tid & 63;
    const int row0 = blockIdx.x * 128;
    const int cb = blockIdx.y;

    const u16 *Wh, *Wl = nullptr; const float* bias;
    int n0, path;
    if (cb < 2)      { path = 0; n0 = cb * 128;       Wh = WxTh; Wl = WxTl; bias = bx; }
    else if (cb < 4) { path = 1; n0 = (cb - 2) * 128; Wh = WyTh; Wl = WyTl; bias = by; }
    else             { path = 2; n0 = (cb - 4) * 128; Wh = WoTh;            bias = bo; }
    const bool split = (path != 2);

    f32x4 acc[4][4] = {};
    const int wm = (w & 1) * 64, wn = (w >> 1) * 64;
    const int fr = lane & 15, fq = lane >> 4;
    const int sr = lane >> 2, sc = (lane & 3) * 8;

    for (int k0 = 0; k0 < NC; k0 += 32) {
#pragma unroll
        for (int t = 0; t < 2; ++t) {
            const int rb = (w * 2 + t) * 16;
            const size_t ar = (size_t)(row0 + rb + sr) * NC + k0 + sc;
            const size_t br = (size_t)(n0 + rb + sr) * NC + k0 + sc;
            gload16(Xh + ar, (char*)As + rb * 64);
            gload16(Wh + br, (char*)Bs + rb * 64);
            if (split) {
                gload16(Xl + ar, (char*)Als + rb * 64);
                gload16(Wl + br, (char*)Bls + rb * 64);
            }
        }
        __syncthreads();
        bf16x8 ah[4], bh[4], al[4], bl[4];
#pragma unroll
        for (int mi = 0; mi < 4; ++mi)
            ah[mi] = *(const bf16x8*)&As[(wm + mi * 16 + fr) * 32 + fq * 8];
#pragma unroll
        for (int ni = 0; ni < 4; ++ni)
            bh[ni] = *(const bf16x8*)&Bs[(wn + ni * 16 + fr) * 32 + fq * 8];
        if (split) {
#pragma unroll
            for (int mi = 0; mi < 4; ++mi)
                al[mi] = *(const bf16x8*)&Als[(wm + mi * 16 + fr) * 32 + fq * 8];
#pragma unroll
            for (int ni = 0; ni < 4; ++ni)
                bl[ni] = *(const bf16x8*)&Bls[(wn + ni * 16 + fr) * 32 + fq * 8];
        }
#pragma unroll
        for (int mi = 0; mi < 4; ++mi)
#pragma unroll
            for (int ni = 0; ni < 4; ++ni) {
                acc[mi][ni] = __builtin_amdgcn_mfma_f32_16x16x32_bf16(ah[mi], bh[ni], acc[mi][ni], 0, 0, 0);
                if (split) {
                    acc[mi][ni] = __builtin_amdgcn_mfma_f32_16x16x32_bf16(ah[mi], bl[ni], acc[mi][ni], 0, 0, 0);
                    acc[mi][ni] = __builtin_amdgcn_mfma_f32_16x16x32_bf16(al[mi], bh[ni], acc[mi][ni], 0, 0, 0);
                }
            }
        __syncthreads();
    }

    if (split) {
        u16* OH = (path == 0) ? xph : yph;
        u16* OL = (path == 0) ? xpl : ypl;
#pragma unroll
        for (int mi = 0; mi < 4; ++mi) {
            const int grow = row0 + wm + mi * 16 + fq * 4;
#pragma unroll
            for (int ni = 0; ni < 4; ++ni) {
                const int gcol = n0 + wn + ni * 16 + fr;
                const float bv = bias[gcol];
#pragma unroll
                for (int r = 0; r < 4; ++r) {
                    u16 h, l; split2(acc[mi][ni][r] + bv, h, l);
                    const size_t off = (size_t)(grow + r) * NCI + gcol;
                    OH[off] = h; OL[off] = l;
                }
            }
        }
    } else {
        u16* Ts = SM;   // 128 x 136 bf16 transpose staging (stride 272B, 16B-aligned)
#pragma unroll
        for (int mi = 0; mi < 4; ++mi) {
            const int mb = wm + mi * 16 + fq * 4;
#pragma unroll
            for (int ni = 0; ni < 4; ++ni) {
                const int nl_ = wn + ni * 16 + fr;
                const float bv = bias[n0 + nl_];
#pragma unroll
                for (int r = 0; r < 4; ++r)
                    Ts[nl_ * 136 + mb + r] = (u16)bf16rn(acc[mi][ni][r] + bv);
            }
        }
        __syncthreads();
        const int b = row0 >> 11, m0 = row0 & 2047;
        u16* dst = opT + (size_t)b * NC * NL + (size_t)n0 * NL + m0;
        for (int i = tid; i < 128 * 16; i += 256) {
            const int c = i >> 4, ch = i & 15;
            uint4 v = *(const uint4*)&Ts[c * 136 + ch * 8];
            *(uint4*)&dst[(size_t)c * NL + ch * 8] = v;
        }
    }
}

// ---- scores: S16[b] = fp16( xp[b] @ yp[b]^T ), split bf16 (3 MFMAs) --------
__global__ __launch_bounds__(256) void score_kernel(
    const u16* __restrict__ xph, const u16* __restrict__ xpl,
    const u16* __restrict__ yph, const u16* __restrict__ ypl,
    u16* __restrict__ S16)
{
    __shared__ __align__(16) u16 As[4096], Als[4096], Bs[4096], Bls[4096];
    const int tid = threadIdx.x;
    const int w = tid >> 6, lane = tid & 63;
    const int b = blockIdx.z;
    const int row0 = blockIdx.x * 128, col0 = blockIdx.y * 128;
    const size_t ab = (size_t)b * NL * NCI;
    const u16* Ah = xph + ab; const u16* Al = xpl + ab;
    const u16* Bh = yph + ab; const u16* Bl = ypl + ab;

    f32x4 acc[4][4] = {};
    const int wm = (w & 1) * 64, wn = (w >> 1) * 64;
    const int fr = lane & 15, fq = lane >> 4;
    const int sr = lane >> 2, sc = (lane & 3) * 8;

    for (int k0 = 0; k0 < NCI; k0 += 32) {
#pragma unroll
        for (int t = 0; t < 2; ++t) {
            const int rb = (w * 2 + t) * 16;
            const size_t ar = (size_t)(row0 + rb + sr) * NCI + k0 + sc;
            const size_t br = (size_t)(col0 + rb + sr) * NCI + k0 + sc;
            gload16(Ah + ar, (char*)As + rb * 64);
            gload16(Al + ar, (char*)Als + rb * 64);
            gload16(Bh + br, (char*)Bs + rb * 64);
            gload16(Bl + br, (char*)Bls + rb * 64);
        }
        __syncthreads();
        bf16x8 ah[4], al[4], bh[4], bl[4];
#pragma unroll
        for (int mi = 0; mi < 4; ++mi) {
            ah[mi] = *(const bf16x8*)&As[(wm + mi * 16 + fr) * 32 + fq * 8];
            al[mi] = *(const bf16x8*)&Als[(wm + mi * 16 + fr) * 32 + fq * 8];
        }
#pragma unroll
        for (int ni = 0; ni < 4; ++ni) {
            bh[ni] = *(const bf16x8*)&Bs[(wn + ni * 16 + fr) * 32 + fq * 8];
            bl[ni] = *(const bf16x8*)&Bls[(wn + ni * 16 + fr) * 32 + fq * 8];
        }
#pragma unroll
        for (int mi = 0; mi < 4; ++mi)
#pragma unroll
            for (int ni = 0; ni < 4; ++ni) {
                acc[mi][ni] = __builtin_amdgcn_mfma_f32_16x16x32_bf16(ah[mi], bh[ni], acc[mi][ni], 0, 0, 0);
                acc[mi][ni] = __builtin_amdgcn_mfma_f32_16x16x32_bf16(ah[mi], bl[ni], acc[mi][ni], 0, 0, 0);
                acc[mi][ni] = __builtin_amdgcn_mfma_f32_16x16x32_bf16(al[mi], bh[ni], acc[mi][ni], 0, 0, 0);
            }
        __syncthreads();
    }
    u16* Sb = S16 + (size_t)b * NL * NL;
#pragma unroll
    for (int mi = 0; mi < 4; ++mi) {
        const int gr = row0 + wm + mi * 16 + fq * 4;
#pragma unroll
        for (int ni = 0; ni < 4; ++ni) {
            const int gc = col0 + wn + ni * 16 + fr;
#pragma unroll
            for (int r = 0; r < 4; ++r) {
                _Float16 h = (_Float16)acc[mi][ni][r];
                Sb[(size_t)(gr + r) * NL + gc] = __builtin_bit_cast(u16, h);
            }
        }
    }
}

// ---- softmax over batch axis, fp16 in -> compact bf16 attn, IN PLACE ------
// Each thread owns 8 consecutive positions x 8 batches (same u16 slots).
__global__ __launch_bounds__(256) void softmax_kernel(u16* __restrict__ S16)
{
    const size_t g = (size_t)blockIdx.x * 256 + threadIdx.x;   // uint4 group (8 u16)
    const size_t st = (size_t)NL * NL / 8;                     // uint4 per batch
    uint4* P = (uint4*)S16;
    uint4 raw[NB];
#pragma unroll
    for (int b = 0; b < NB; ++b) raw[b] = P[b * st + g];
    float f[NB][8];
#pragma unroll
    for (int b = 0; b < NB; ++b) {
        f16x8 h = __builtin_bit_cast(f16x8, raw[b]);
#pragma unroll
        for (int j = 0; j < 8; ++j) f[b][j] = (float)h[j];
    }
#pragma unroll
    for (int j = 0; j < 8; ++j) {
        float mx = f[0][j];
#pragma unroll
        for (int b = 1; b < NB; ++b) mx = fmaxf(mx, f[b][j]);
        float s = 0.f;
#pragma unroll
        for (int b = 0; b < NB; ++b) { f[b][j] = __expf(f[b][j] - mx); s += f[b][j]; }
        const float inv = 1.f / s;
#pragma unroll
        for (int b = 0; b < NB; ++b) f[b][j] *= inv;
    }
#pragma unroll
    for (int b = 0; b < NB; ++b) {
        ushort o[8];
#pragma unroll
        for (int j = 0; j < 8; ++j) o[j] = (u16)bf16rn(f[b][j]);
        P[b * st + g] = *(const uint4*)o;
    }
}

// ---- out: out[b] = X[b] + attn[b] @ op[b], plain bf16 MFMA -----------------
// A = compact bf16 attn (in S16's storage), staged via global_load_lds.
__global__ __launch_bounds__(256) void out_kernel(
    const u16* __restrict__ S16, const u16* __restrict__ opT,
    const float* __restrict__ X, float* __restrict__ Out)
{
    __shared__ __align__(16) u16 As[4096], Bs[4096];
    const int tid = threadIdx.x;
    const int w = tid >> 6, lane = tid & 63;
    const int b = blockIdx.z;
    const int row0 = blockIdx.x * 128, col0 = blockIdx.y * 128;
    const u16* Aatt = S16 + (size_t)b * NL * NL;
    const u16* Bsrc = opT + (size_t)b * NC * NL;

    f32x4 acc[4][4] = {};
    const int wm = (w & 1) * 64, wn = (w >> 1) * 64;
    const int fr = lane & 15, fq = lane >> 4;
    const int sr = lane >> 2, sc = (lane & 3) * 8;

    for (int k0 = 0; k0 < NL; k0 += 32) {
#pragma unroll
        for (int t = 0; t < 2; ++t) {
            const int rb = (w * 2 + t) * 16;
            gload16(Aatt + (size_t)(row0 + rb + sr) * NL + k0 + sc, (char*)As + rb * 64);
            gload16(Bsrc + (size_t)(col0 + rb + sr) * NL + k0 + sc, (char*)Bs + rb * 64);
        }
        __syncthreads();
        bf16x8 af[4], bfr[4];
#pragma unroll
        for (int mi = 0; mi < 4; ++mi)
            af[mi] = *(const bf16x8*)&As[(wm + mi * 16 + fr) * 32 + fq * 8];
#pragma unroll
        for (int ni = 0; ni < 4; ++ni)
            bfr[ni] = *(const bf16x8*)&Bs[(wn + ni * 16 + fr) * 32 + fq * 8];
#pragma unroll
        for (int mi = 0; mi < 4; ++mi)
#pragma unroll
            for (int ni = 0; ni < 4; ++ni)
                acc[mi][ni] = __builtin_amdgcn_mfma_f32_16x16x32_bf16(af[mi], bfr[ni], acc[mi][ni], 0, 0, 0);
        __syncthreads();
    }
    const size_t ob = (size_t)b * NL * NC;
#pragma unroll
    for (int mi = 0; mi < 4; ++mi) {
        const int gr = row0 + wm + mi * 16 + fq * 4;
#pragma unroll
        for (int ni = 0; ni < 4; ++ni) {
            const int gc = col0 + wn + ni * 16 + fr;
#pragma unroll
            for (int r = 0; r < 4; ++r) {
                const size_t o = ob + (size_t)(gr + r) * NC + gc;
                Out[o] = X[o] + acc[mi][ni][r];
            }
        }
    }
}

extern "C" void kernel_launch(void* const* d_in, const int* in_sizes, int n_in,
                              void* d_out, int out_size, void* d_ws, size_t ws_size,
                              hipStream_t stream)
{
    const float* X  = (const float*)d_in[0];
    const float* Wx = (const float*)d_in[1];
    const float* bx = (const float*)d_in[2];
    const float* Wy = (const float*)d_in[3];
    const float* by = (const float*)d_in[4];
    const float* Wo = (const float*)d_in[5];
    const float* bo = (const float*)d_in[6];
    float* out = (float*)d_out;

    // Workspace (~117 MB):
    //   S16 u16 [0, 64MB) — Xh/Xl (bf16, 16MB each) overlap S16[0:32MB); they are
    //   dead (proj done) before score_kernel writes S16 (stream-ordered).
    char* ws = (char*)d_ws;
    u16* S16 = (u16*)ws;
    u16* Xh  = (u16*)ws;
    u16* Xl  = (u16*)(ws + 16777216);
    char* p = ws + 67108864;
    u16* xph = (u16*)p;  p += 8388608;
    u16* xpl = (u16*)p;  p += 8388608;
    u16* yph = (u16*)p;  p += 8388608;
    u16* ypl = (u16*)p;  p += 8388608;
    u16* opT = (u16*)p;  p += 16777216;
    u16* WxTh = (u16*)p; p += 262144;
    u16* WxTl = (u16*)p; p += 262144;
    u16* WyTh = (u16*)p; p += 262144;
    u16* WyTl = (u16*)p; p += 262144;
    u16* WoTh = (u16*)p; p += 524288;

    cvt_x_kernel<<<8192, 256, 0, stream>>>(X, Xh, Xl);
    cvt_w_kernel<<<1024, 256, 0, stream>>>(Wx, Wy, Wo, WxTh, WxTl, WyTh, WyTl, WoTh);
    proj_kernel<<<dim3(128, 8), 256, 0, stream>>>(Xh, Xl, WxTh, WxTl, WyTh, WyTl, WoTh,
                                                  bx, by, bo, xph, xpl, yph, ypl, opT);
    score_kernel<<<dim3(16, 16, NB), 256, 0, stream>>>(xph, xpl, yph, ypl, S16);
    softmax_kernel<<<2048, 256, 0, stream>>>(S16);
    out_kernel<<<dim3(16, 4, NB), 256, 0, stream>>>(S16, opT, X, out);
}

// Round 4
// 220.899 us; speedup vs baseline: 5.1365x; 1.2706x over previous
//
#include <hip/hip_runtime.h>

// NonLocalBlock B=8, L=2048, C=512, CI=256 (fp32 in/out).
// Round 4: all-fp16 pipeline (error budget verified: measured 0.5 absmax at
// round 3 scales to ~1.2 predicted vs 2.92 threshold).
//   X, W, xp, yp, scores, attn, opT all fp16; single mfma_f32_16x16x32_f16
//   per tile-step everywhere (3x less MFMA work on score chain vs split-bf16).
//   out_kernel: BK=64 (half the barrier drains). All tiles use XOR k-chunk
//   swizzle (consistent at stage+read; global_load_lds-legal) to kill LDS
//   fragment-read bank conflicts.

#define NB 8
#define NL 2048
#define NC 512
#define NCI 256

using f16x8 = __attribute__((ext_vector_type(8))) _Float16;
using f32x4 = __attribute__((ext_vector_type(4))) float;
typedef unsigned short u16;

__device__ __forceinline__ u16 f16b(float x) {
    _Float16 h = (_Float16)x;
    return __builtin_bit_cast(u16, h);
}
__device__ __forceinline__ void gload16(const void* g, void* l) {
    __builtin_amdgcn_global_load_lds((__attribute__((address_space(1))) void*)g,
                                     (__attribute__((address_space(3))) void*)l,
                                     16, 0, 0);
}

// ---- cvt: X fp32 -> fp16 --------------------------------------------------
__global__ __launch_bounds__(256) void cvt_x_kernel(const float* __restrict__ X,
                                                    u16* __restrict__ Xf)
{
    size_t i = (size_t)blockIdx.x * 256 + threadIdx.x;   // per 8 elements
    const float4* X4 = (const float4*)X;
    float4 a = X4[2 * i], b = X4[2 * i + 1];
    u16 o[8] = {f16b(a.x), f16b(a.y), f16b(a.z), f16b(a.w),
                f16b(b.x), f16b(b.y), f16b(b.z), f16b(b.w)};
    ((uint4*)Xf)[i] = *(const uint4*)o;
}

// ---- cvt: transpose weights to [n][k] fp16 --------------------------------
__global__ __launch_bounds__(256) void cvt_w_kernel(
    const float* __restrict__ Wx, const float* __restrict__ Wy, const float* __restrict__ Wo,
    u16* __restrict__ WxT, u16* __restrict__ WyT, u16* __restrict__ WoT)
{
    const int bid = blockIdx.x, t = threadIdx.x;
#pragma unroll
    for (int kk = 0; kk < 2; ++kk) {
        const int k = t + kk * 256;
        if (bid < 256)      WxT[(size_t)bid * NC + k] = f16b(Wx[(size_t)k * NCI + bid]);
        else if (bid < 512) WyT[(size_t)(bid - 256) * NC + k] = f16b(Wy[(size_t)k * NCI + (bid - 256)]);
        else                WoT[(size_t)(bid - 512) * NC + k] = f16b(Wo[(size_t)k * NC + (bid - 512)]);
    }
}

// ---- projections: grid (128, 8); cb 0-1 xp, 2-3 yp, 4-7 op (transposed) ----
__global__ __launch_bounds__(256) void proj_kernel(
    const u16* __restrict__ Xf,
    const u16* __restrict__ WxT, const u16* __restrict__ WyT, const u16* __restrict__ WoT,
    const float* __restrict__ bx, const float* __restrict__ by, const float* __restrict__ bo,
    u16* __restrict__ xp, u16* __restrict__ yp, u16* __restrict__ opT)
{
    __shared__ __align__(16) u16 SM[17408];   // As 4096 + Bs 4096; Ts reuse 128x136
    u16* As = SM;
    u16* Bs = SM + 4096;

    const int tid = threadIdx.x;
    const int w = tid >> 6, lane = tid & 63;
    const int row0 = blockIdx.x * 128;
    const int cb = blockIdx.y;

    const u16* W; const float* bias; int n0, path;
    if (cb < 2)      { path = 0; n0 = cb * 128;       W = WxT; bias = bx; }
    else if (cb < 4) { path = 1; n0 = (cb - 2) * 128; W = WyT; bias = by; }
    else             { path = 2; n0 = (cb - 4) * 128; W = WoT; bias = bo; }

    f32x4 acc[4][4] = {};
    const int wm = (w & 1) * 64, wn = (w >> 1) * 64;
    const int fr = lane & 15, fq = lane >> 4;
    const int sr = lane >> 2;
    const int sc = ((lane & 3) ^ (sr & 3)) * 8;   // XOR-swizzled k-chunk

    for (int k0 = 0; k0 < NC; k0 += 32) {
#pragma unroll
        for (int t = 0; t < 2; ++t) {
            const int rb = (w * 2 + t) * 16;
            gload16(Xf + (size_t)(row0 + rb + sr) * NC + k0 + sc, (char*)As + rb * 64);
            gload16(W  + (size_t)(n0  + rb + sr) * NC + k0 + sc, (char*)Bs + rb * 64);
        }
        __syncthreads();
        f16x8 a[4], b[4];
#pragma unroll
        for (int mi = 0; mi < 4; ++mi)
            a[mi] = *(const f16x8*)&As[(wm + mi * 16 + fr) * 32 + (fq ^ (fr & 3)) * 8];
#pragma unroll
        for (int ni = 0; ni < 4; ++ni)
            b[ni] = *(const f16x8*)&Bs[(wn + ni * 16 + fr) * 32 + (fq ^ (fr & 3)) * 8];
#pragma unroll
        for (int mi = 0; mi < 4; ++mi)
#pragma unroll
            for (int ni = 0; ni < 4; ++ni)
                acc[mi][ni] = __builtin_amdgcn_mfma_f32_16x16x32_f16(a[mi], b[ni], acc[mi][ni], 0, 0, 0);
        __syncthreads();
    }

    if (path != 2) {
        u16* O = (path == 0) ? xp : yp;
#pragma unroll
        for (int mi = 0; mi < 4; ++mi) {
            const int grow = row0 + wm + mi * 16 + fq * 4;
#pragma unroll
            for (int ni = 0; ni < 4; ++ni) {
                const int gcol = n0 + wn + ni * 16 + fr;
                const float bv = bias[gcol];
#pragma unroll
                for (int r = 0; r < 4; ++r)
                    O[(size_t)(grow + r) * NCI + gcol] = f16b(acc[mi][ni][r] + bv);
            }
        }
    } else {
        u16* Ts = SM;   // 128 x 136 fp16 transpose staging
#pragma unroll
        for (int mi = 0; mi < 4; ++mi) {
            const int mb = wm + mi * 16 + fq * 4;
#pragma unroll
            for (int ni = 0; ni < 4; ++ni) {
                const int nl_ = wn + ni * 16 + fr;
                const float bv = bias[n0 + nl_];
#pragma unroll
                for (int r = 0; r < 4; ++r)
                    Ts[nl_ * 136 + mb + r] = f16b(acc[mi][ni][r] + bv);
            }
        }
        __syncthreads();
        const int b = row0 >> 11, m0 = row0 & 2047;
        u16* dst = opT + (size_t)b * NC * NL + (size_t)n0 * NL + m0;
        for (int i = tid; i < 128 * 16; i += 256) {
            const int c = i >> 4, ch = i & 15;
            uint4 v = *(const uint4*)&Ts[c * 136 + ch * 8];
            *(uint4*)&dst[(size_t)c * NL + ch * 8] = v;
        }
    }
}

// ---- scores: S16[b] = fp16( xp[b] @ yp[b]^T ), single fp16 MFMA ------------
__global__ __launch_bounds__(256) void score_kernel(
    const u16* __restrict__ xp, const u16* __restrict__ yp, u16* __restrict__ S16)
{
    __shared__ __align__(16) u16 As[4096], Bs[4096];
    const int tid = threadIdx.x;
    const int w = tid >> 6, lane = tid & 63;
    const int b = blockIdx.z;
    const int row0 = blockIdx.x * 128, col0 = blockIdx.y * 128;
    const size_t ab = (size_t)b * NL * NCI;
    const u16* A = xp + ab;
    const u16* B = yp + ab;

    f32x4 acc[4][4] = {};
    const int wm = (w & 1) * 64, wn = (w >> 1) * 64;
    const int fr = lane & 15, fq = lane >> 4;
    const int sr = lane >> 2;
    const int sc = ((lane & 3) ^ (sr & 3)) * 8;

    for (int k0 = 0; k0 < NCI; k0 += 32) {
#pragma unroll
        for (int t = 0; t < 2; ++t) {
            const int rb = (w * 2 + t) * 16;
            gload16(A + (size_t)(row0 + rb + sr) * NCI + k0 + sc, (char*)As + rb * 64);
            gload16(B + (size_t)(col0 + rb + sr) * NCI + k0 + sc, (char*)Bs + rb * 64);
        }
        __syncthreads();
        f16x8 a[4], bfr[4];
#pragma unroll
        for (int mi = 0; mi < 4; ++mi)
            a[mi] = *(const f16x8*)&As[(wm + mi * 16 + fr) * 32 + (fq ^ (fr & 3)) * 8];
#pragma unroll
        for (int ni = 0; ni < 4; ++ni)
            bfr[ni] = *(const f16x8*)&Bs[(wn + ni * 16 + fr) * 32 + (fq ^ (fr & 3)) * 8];
#pragma unroll
        for (int mi = 0; mi < 4; ++mi)
#pragma unroll
            for (int ni = 0; ni < 4; ++ni)
                acc[mi][ni] = __builtin_amdgcn_mfma_f32_16x16x32_f16(a[mi], bfr[ni], acc[mi][ni], 0, 0, 0);
        __syncthreads();
    }
    u16* Sb = S16 + (size_t)b * NL * NL;
#pragma unroll
    for (int mi = 0; mi < 4; ++mi) {
        const int gr = row0 + wm + mi * 16 + fq * 4;
#pragma unroll
        for (int ni = 0; ni < 4; ++ni) {
            const int gc = col0 + wn + ni * 16 + fr;
#pragma unroll
            for (int r = 0; r < 4; ++r)
                Sb[(size_t)(gr + r) * NL + gc] = f16b(acc[mi][ni][r]);
        }
    }
}

// ---- softmax over batch axis, fp16 in -> fp16 attn, IN PLACE ---------------
__global__ __launch_bounds__(256) void softmax_kernel(u16* __restrict__ S16)
{
    const size_t g = (size_t)blockIdx.x * 256 + threadIdx.x;   // uint4 group (8 u16)
    const size_t st = (size_t)NL * NL / 8;
    uint4* P = (uint4*)S16;
    uint4 raw[NB];
#pragma unroll
    for (int b = 0; b < NB; ++b) raw[b] = P[b * st + g];
    float f[NB][8];
#pragma unroll
    for (int b = 0; b < NB; ++b) {
        f16x8 h = __builtin_bit_cast(f16x8, raw[b]);
#pragma unroll
        for (int j = 0; j < 8; ++j) f[b][j] = (float)h[j];
    }
#pragma unroll
    for (int j = 0; j < 8; ++j) {
        float mx = f[0][j];
#pragma unroll
        for (int b = 1; b < NB; ++b) mx = fmaxf(mx, f[b][j]);
        float s = 0.f;
#pragma unroll
        for (int b = 0; b < NB; ++b) { f[b][j] = __expf(f[b][j] - mx); s += f[b][j]; }
        const float inv = 1.f / s;
#pragma unroll
        for (int b = 0; b < NB; ++b) f[b][j] *= inv;
    }
#pragma unroll
    for (int b = 0; b < NB; ++b) {
        u16 o[8];
#pragma unroll
        for (int j = 0; j < 8; ++j) o[j] = f16b(f[b][j]);
        P[b * st + g] = *(const uint4*)o;
    }
}

// ---- out: out[b] = X[b] + attn[b] @ op[b], fp16 MFMA, BK=64 ----------------
__global__ __launch_bounds__(256) void out_kernel(
    const u16* __restrict__ S16, const u16* __restrict__ opT,
    const float* __restrict__ X, float* __restrict__ Out)
{
    __shared__ __align__(16) u16 As[8192], Bs[8192];   // 128 x 64 each
    const int tid = threadIdx.x;
    const int w = tid >> 6, lane = tid & 63;
    const int b = blockIdx.z;
    const int row0 = blockIdx.x * 128, col0 = blockIdx.y * 128;
    const u16* Aatt = S16 + (size_t)b * NL * NL;
    const u16* Bsrc = opT + (size_t)b * NC * NL;

    f32x4 acc[4][4] = {};
    const int wm = (w & 1) * 64, wn = (w >> 1) * 64;
    const int fr = lane & 15, fq = lane >> 4;

    for (int k0 = 0; k0 < NL; k0 += 64) {
#pragma unroll
        for (int i = 0; i < 4; ++i) {
            const int cbase = i * 256 + w * 64;      // wave-uniform chunk base
            const int chunk = cbase + lane;
            const int r = chunk >> 3;
            const int kc = (chunk & 7) ^ (r & 7);    // XOR-swizzled k-chunk
            gload16(Aatt + (size_t)(row0 + r) * NL + k0 + kc * 8, (char*)As + cbase * 16);
            gload16(Bsrc + (size_t)(col0 + r) * NL + k0 + kc * 8, (char*)Bs + cbase * 16);
        }
        __syncthreads();
        f16x8 af[4][2], bf[4][2];
#pragma unroll
        for (int mi = 0; mi < 4; ++mi)
#pragma unroll
            for (int kt = 0; kt < 2; ++kt)
                af[mi][kt] = *(const f16x8*)&As[(wm + mi * 16 + fr) * 64 + ((kt * 4 + fq) ^ (fr & 7)) * 8];
#pragma unroll
        for (int ni = 0; ni < 4; ++ni)
#pragma unroll
            for (int kt = 0; kt < 2; ++kt)
                bf[ni][kt] = *(const f16x8*)&Bs[(wn + ni * 16 + fr) * 64 + ((kt * 4 + fq) ^ (fr & 7)) * 8];
#pragma unroll
        for (int kt = 0; kt < 2; ++kt)
#pragma unroll
            for (int mi = 0; mi < 4; ++mi)
#pragma unroll
                for (int ni = 0; ni < 4; ++ni)
                    acc[mi][ni] = __builtin_amdgcn_mfma_f32_16x16x32_f16(af[mi][kt], bf[ni][kt], acc[mi][ni], 0, 0, 0);
        __syncthreads();
    }
    const size_t ob = (size_t)b * NL * NC;
#pragma unroll
    for (int mi = 0; mi < 4; ++mi) {
        const int gr = row0 + wm + mi * 16 + fq * 4;
#pragma unroll
        for (int ni = 0; ni < 4; ++ni) {
            const int gc = col0 + wn + ni * 16 + fr;
#pragma unroll
            for (int r = 0; r < 4; ++r) {
                const size_t o = ob + (size_t)(gr + r) * NC + gc;
                Out[o] = X[o] + acc[mi][ni][r];
            }
        }
    }
}

extern "C" void kernel_launch(void* const* d_in, const int* in_sizes, int n_in,
                              void* d_out, int out_size, void* d_ws, size_t ws_size,
                              hipStream_t stream)
{
    const float* X  = (const float*)d_in[0];
    const float* Wx = (const float*)d_in[1];
    const float* bx = (const float*)d_in[2];
    const float* Wy = (const float*)d_in[3];
    const float* by = (const float*)d_in[4];
    const float* Wo = (const float*)d_in[5];
    const float* bo = (const float*)d_in[6];
    float* out = (float*)d_out;

    // Workspace (~97 MB): S16 [0,64MB); Xf16 (16MB) overlaps S16[0:16MB) — dead
    // (proj done) before score_kernel writes S16 (stream-ordered).
    char* ws = (char*)d_ws;
    u16* S16 = (u16*)ws;
    u16* Xf  = (u16*)ws;
    char* p = ws + 67108864;
    u16* xp  = (u16*)p; p += 8388608;
    u16* yp  = (u16*)p; p += 8388608;
    u16* opT = (u16*)p; p += 16777216;
    u16* WxT = (u16*)p; p += 262144;
    u16* WyT = (u16*)p; p += 262144;
    u16* WoT = (u16*)p; p += 524288;

    cvt_x_kernel<<<4096, 256, 0, stream>>>(X, Xf);
    cvt_w_kernel<<<1024, 256, 0, stream>>>(Wx, Wy, Wo, WxT, WyT, WoT);
    proj_kernel<<<dim3(128, 8), 256, 0, stream>>>(Xf, WxT, WyT, WoT, bx, by, bo, xp, yp, opT);
    score_kernel<<<dim3(16, 16, NB), 256, 0, stream>>>(xp, yp, S16);
    softmax_kernel<<<2048, 256, 0, stream>>>(S16);
    out_kernel<<<dim3(16, 4, NB), 256, 0, stream>>>(S16, opT, X, out);
}

// Round 5
// 219.835 us; speedup vs baseline: 5.1613x; 1.0048x over previous
//
#include <hip/hip_runtime.h>

// NonLocalBlock B=8, L=2048, C=512, CI=256 (fp32 in/out).
// Round 5: occupancy fix on out_kernel (512 threads / 8 waves, 128x128 tile,
// BK=64 -> 16 waves/CU at 2 blocks/CU); BK=64 on score & proj to halve
// barrier drains. All-fp16 pipeline, XOR k-chunk swizzle (0 bank conflicts).

#define NB 8
#define NL 2048
#define NC 512
#define NCI 256

using f16x8 = __attribute__((ext_vector_type(8))) _Float16;
using f32x4 = __attribute__((ext_vector_type(4))) float;
typedef unsigned short u16;

__device__ __forceinline__ u16 f16b(float x) {
    _Float16 h = (_Float16)x;
    return __builtin_bit_cast(u16, h);
}
__device__ __forceinline__ void gload16(const void* g, void* l) {
    __builtin_amdgcn_global_load_lds((__attribute__((address_space(1))) void*)g,
                                     (__attribute__((address_space(3))) void*)l,
                                     16, 0, 0);
}

// ---- cvt: X fp32 -> fp16 --------------------------------------------------
__global__ __launch_bounds__(256) void cvt_x_kernel(const float* __restrict__ X,
                                                    u16* __restrict__ Xf)
{
    size_t i = (size_t)blockIdx.x * 256 + threadIdx.x;   // per 8 elements
    const float4* X4 = (const float4*)X;
    float4 a = X4[2 * i], b = X4[2 * i + 1];
    u16 o[8] = {f16b(a.x), f16b(a.y), f16b(a.z), f16b(a.w),
                f16b(b.x), f16b(b.y), f16b(b.z), f16b(b.w)};
    ((uint4*)Xf)[i] = *(const uint4*)o;
}

// ---- cvt: transpose weights to [n][k] fp16 --------------------------------
__global__ __launch_bounds__(256) void cvt_w_kernel(
    const float* __restrict__ Wx, const float* __restrict__ Wy, const float* __restrict__ Wo,
    u16* __restrict__ WxT, u16* __restrict__ WyT, u16* __restrict__ WoT)
{
    const int bid = blockIdx.x, t = threadIdx.x;
#pragma unroll
    for (int kk = 0; kk < 2; ++kk) {
        const int k = t + kk * 256;
        if (bid < 256)      WxT[(size_t)bid * NC + k] = f16b(Wx[(size_t)k * NCI + bid]);
        else if (bid < 512) WyT[(size_t)(bid - 256) * NC + k] = f16b(Wy[(size_t)k * NCI + (bid - 256)]);
        else                WoT[(size_t)(bid - 512) * NC + k] = f16b(Wo[(size_t)k * NC + (bid - 512)]);
    }
}

// ---- projections: grid (128, 8); cb 0-1 xp, 2-3 yp, 4-7 op (transposed) ----
// 256 threads, 4 waves (2x2 of 64x64), 128x128 tile, BK=64.
__global__ __launch_bounds__(256) void proj_kernel(
    const u16* __restrict__ Xf,
    const u16* __restrict__ WxT, const u16* __restrict__ WyT, const u16* __restrict__ WoT,
    const float* __restrict__ bx, const float* __restrict__ by, const float* __restrict__ bo,
    u16* __restrict__ xp, u16* __restrict__ yp, u16* __restrict__ opT)
{
    __shared__ __align__(16) u16 SM[17408];   // As 8192 + Bs 8192; Ts reuse 128x136
    u16* As = SM;
    u16* Bs = SM + 8192;

    const int tid = threadIdx.x;
    const int w = tid >> 6, lane = tid & 63;
    const int row0 = blockIdx.x * 128;
    const int cb = blockIdx.y;

    const u16* W; const float* bias; int n0, path;
    if (cb < 2)      { path = 0; n0 = cb * 128;       W = WxT; bias = bx; }
    else if (cb < 4) { path = 1; n0 = (cb - 2) * 128; W = WyT; bias = by; }
    else             { path = 2; n0 = (cb - 4) * 128; W = WoT; bias = bo; }

    f32x4 acc[4][4] = {};
    const int wm = (w & 1) * 64, wn = (w >> 1) * 64;
    const int fr = lane & 15, fq = lane >> 4;

    for (int k0 = 0; k0 < NC; k0 += 64) {
#pragma unroll
        for (int pass = 0; pass < 4; ++pass) {
            const int cbase = pass * 256 + w * 64;   // wave-uniform
            const int chunk = cbase + lane;
            const int r = chunk >> 3;
            const int kc = (chunk & 7) ^ (r & 7);    // XOR-swizzled k-chunk
            gload16(Xf + (size_t)(row0 + r) * NC + k0 + kc * 8, (char*)As + cbase * 16);
            gload16(W  + (size_t)(n0  + r) * NC + k0 + kc * 8, (char*)Bs + cbase * 16);
        }
        __syncthreads();
        f16x8 a[4][2], b[4][2];
#pragma unroll
        for (int mi = 0; mi < 4; ++mi)
#pragma unroll
            for (int kt = 0; kt < 2; ++kt)
                a[mi][kt] = *(const f16x8*)&As[(wm + mi * 16 + fr) * 64 + ((kt * 4 + fq) ^ (fr & 7)) * 8];
#pragma unroll
        for (int ni = 0; ni < 4; ++ni)
#pragma unroll
            for (int kt = 0; kt < 2; ++kt)
                b[ni][kt] = *(const f16x8*)&Bs[(wn + ni * 16 + fr) * 64 + ((kt * 4 + fq) ^ (fr & 7)) * 8];
#pragma unroll
        for (int kt = 0; kt < 2; ++kt)
#pragma unroll
            for (int mi = 0; mi < 4; ++mi)
#pragma unroll
                for (int ni = 0; ni < 4; ++ni)
                    acc[mi][ni] = __builtin_amdgcn_mfma_f32_16x16x32_f16(a[mi][kt], b[ni][kt], acc[mi][ni], 0, 0, 0);
        __syncthreads();
    }

    if (path != 2) {
        u16* O = (path == 0) ? xp : yp;
#pragma unroll
        for (int mi = 0; mi < 4; ++mi) {
            const int grow = row0 + wm + mi * 16 + fq * 4;
#pragma unroll
            for (int ni = 0; ni < 4; ++ni) {
                const int gcol = n0 + wn + ni * 16 + fr;
                const float bv = bias[gcol];
#pragma unroll
                for (int r = 0; r < 4; ++r)
                    O[(size_t)(grow + r) * NCI + gcol] = f16b(acc[mi][ni][r] + bv);
            }
        }
    } else {
        u16* Ts = SM;   // 128 x 136 fp16 transpose staging
#pragma unroll
        for (int mi = 0; mi < 4; ++mi) {
            const int mb = wm + mi * 16 + fq * 4;
#pragma unroll
            for (int ni = 0; ni < 4; ++ni) {
                const int nl_ = wn + ni * 16 + fr;
                const float bv = bias[n0 + nl_];
#pragma unroll
                for (int r = 0; r < 4; ++r)
                    Ts[nl_ * 136 + mb + r] = f16b(acc[mi][ni][r] + bv);
            }
        }
        __syncthreads();
        const int b = row0 >> 11, m0 = row0 & 2047;
        u16* dst = opT + (size_t)b * NC * NL + (size_t)n0 * NL + m0;
        for (int i = tid; i < 128 * 16; i += 256) {
            const int c = i >> 4, ch = i & 15;
            uint4 v = *(const uint4*)&Ts[c * 136 + ch * 8];
            *(uint4*)&dst[(size_t)c * NL + ch * 8] = v;
        }
    }
}

// ---- scores: S16[b] = fp16( xp[b] @ yp[b]^T ), BK=64 -----------------------
__global__ __launch_bounds__(256) void score_kernel(
    const u16* __restrict__ xp, const u16* __restrict__ yp, u16* __restrict__ S16)
{
    __shared__ __align__(16) u16 As[8192], Bs[8192];   // 128 x 64 each
    const int tid = threadIdx.x;
    const int w = tid >> 6, lane = tid & 63;
    const int b = blockIdx.z;
    const int row0 = blockIdx.x * 128, col0 = blockIdx.y * 128;
    const size_t ab = (size_t)b * NL * NCI;
    const u16* A = xp + ab;
    const u16* B = yp + ab;

    f32x4 acc[4][4] = {};
    const int wm = (w & 1) * 64, wn = (w >> 1) * 64;
    const int fr = lane & 15, fq = lane >> 4;

    for (int k0 = 0; k0 < NCI; k0 += 64) {
#pragma unroll
        for (int pass = 0; pass < 4; ++pass) {
            const int cbase = pass * 256 + w * 64;
            const int chunk = cbase + lane;
            const int r = chunk >> 3;
            const int kc = (chunk & 7) ^ (r & 7);
            gload16(A + (size_t)(row0 + r) * NCI + k0 + kc * 8, (char*)As + cbase * 16);
            gload16(B + (size_t)(col0 + r) * NCI + k0 + kc * 8, (char*)Bs + cbase * 16);
        }
        __syncthreads();
        f16x8 a[4][2], bfr[4][2];
#pragma unroll
        for (int mi = 0; mi < 4; ++mi)
#pragma unroll
            for (int kt = 0; kt < 2; ++kt)
                a[mi][kt] = *(const f16x8*)&As[(wm + mi * 16 + fr) * 64 + ((kt * 4 + fq) ^ (fr & 7)) * 8];
#pragma unroll
        for (int ni = 0; ni < 4; ++ni)
#pragma unroll
            for (int kt = 0; kt < 2; ++kt)
                bfr[ni][kt] = *(const f16x8*)&Bs[(wn + ni * 16 + fr) * 64 + ((kt * 4 + fq) ^ (fr & 7)) * 8];
#pragma unroll
        for (int kt = 0; kt < 2; ++kt)
#pragma unroll
            for (int mi = 0; mi < 4; ++mi)
#pragma unroll
                for (int ni = 0; ni < 4; ++ni)
                    acc[mi][ni] = __builtin_amdgcn_mfma_f32_16x16x32_f16(a[mi][kt], bfr[ni][kt], acc[mi][ni], 0, 0, 0);
        __syncthreads();
    }
    u16* Sb = S16 + (size_t)b * NL * NL;
#pragma unroll
    for (int mi = 0; mi < 4; ++mi) {
        const int gr = row0 + wm + mi * 16 + fq * 4;
#pragma unroll
        for (int ni = 0; ni < 4; ++ni) {
            const int gc = col0 + wn + ni * 16 + fr;
#pragma unroll
            for (int r = 0; r < 4; ++r)
                Sb[(size_t)(gr + r) * NL + gc] = f16b(acc[mi][ni][r]);
        }
    }
}

// ---- softmax over batch axis, fp16 in -> fp16 attn, IN PLACE ---------------
__global__ __launch_bounds__(256) void softmax_kernel(u16* __restrict__ S16)
{
    const size_t g = (size_t)blockIdx.x * 256 + threadIdx.x;   // uint4 group (8 u16)
    const size_t st = (size_t)NL * NL / 8;
    uint4* P = (uint4*)S16;
    uint4 raw[NB];
#pragma unroll
    for (int b = 0; b < NB; ++b) raw[b] = P[b * st + g];
    float f[NB][8];
#pragma unroll
    for (int b = 0; b < NB; ++b) {
        f16x8 h = __builtin_bit_cast(f16x8, raw[b]);
#pragma unroll
        for (int j = 0; j < 8; ++j) f[b][j] = (float)h[j];
    }
#pragma unroll
    for (int j = 0; j < 8; ++j) {
        float mx = f[0][j];
#pragma unroll
        for (int b = 1; b < NB; ++b) mx = fmaxf(mx, f[b][j]);
        float s = 0.f;
#pragma unroll
        for (int b = 0; b < NB; ++b) { f[b][j] = __expf(f[b][j] - mx); s += f[b][j]; }
        const float inv = 1.f / s;
#pragma unroll
        for (int b = 0; b < NB; ++b) f[b][j] *= inv;
    }
#pragma unroll
    for (int b = 0; b < NB; ++b) {
        u16 o[8];
#pragma unroll
        for (int j = 0; j < 8; ++j) o[j] = f16b(f[b][j]);
        P[b * st + g] = *(const uint4*)o;
    }
}

// ---- out: out[b] = X[b] + attn[b] @ op[b], 512 thr / 8 waves, BK=64 --------
// Wave grid 2(m) x 4(n): each wave 64x32 (4x2 MFMAs). 16 waves/CU at 2 blk/CU.
__global__ __launch_bounds__(512) void out_kernel(
    const u16* __restrict__ S16, const u16* __restrict__ opT,
    const float* __restrict__ X, float* __restrict__ Out)
{
    __shared__ __align__(16) u16 As[8192], Bs[8192];   // 128 x 64 each
    const int tid = threadIdx.x;
    const int w = tid >> 6, lane = tid & 63;
    const int b = blockIdx.z;
    const int row0 = blockIdx.x * 128, col0 = blockIdx.y * 128;
    const u16* Aatt = S16 + (size_t)b * NL * NL;
    const u16* Bsrc = opT + (size_t)b * NC * NL;

    f32x4 acc[4][2] = {};
    const int wm = (w & 1) * 64, wn = (w >> 1) * 32;
    const int fr = lane & 15, fq = lane >> 4;

    for (int k0 = 0; k0 < NL; k0 += 64) {
#pragma unroll
        for (int pass = 0; pass < 2; ++pass) {
            const int cbase = pass * 512 + w * 64;   // wave-uniform
            const int chunk = cbase + lane;
            const int r = chunk >> 3;
            const int kc = (chunk & 7) ^ (r & 7);
            gload16(Aatt + (size_t)(row0 + r) * NL + k0 + kc * 8, (char*)As + cbase * 16);
            gload16(Bsrc + (size_t)(col0 + r) * NL + k0 + kc * 8, (char*)Bs + cbase * 16);
        }
        __syncthreads();
        f16x8 af[4][2], bf[2][2];
#pragma unroll
        for (int mi = 0; mi < 4; ++mi)
#pragma unroll
            for (int kt = 0; kt < 2; ++kt)
                af[mi][kt] = *(const f16x8*)&As[(wm + mi * 16 + fr) * 64 + ((kt * 4 + fq) ^ (fr & 7)) * 8];
#pragma unroll
        for (int ni = 0; ni < 2; ++ni)
#pragma unroll
            for (int kt = 0; kt < 2; ++kt)
                bf[ni][kt] = *(const f16x8*)&Bs[(wn + ni * 16 + fr) * 64 + ((kt * 4 + fq) ^ (fr & 7)) * 8];
#pragma unroll
        for (int kt = 0; kt < 2; ++kt)
#pragma unroll
            for (int mi = 0; mi < 4; ++mi)
#pragma unroll
                for (int ni = 0; ni < 2; ++ni)
                    acc[mi][ni] = __builtin_amdgcn_mfma_f32_16x16x32_f16(af[mi][kt], bf[ni][kt], acc[mi][ni], 0, 0, 0);
        __syncthreads();
    }
    const size_t ob = (size_t)b * NL * NC;
#pragma unroll
    for (int mi = 0; mi < 4; ++mi) {
        const int gr = row0 + wm + mi * 16 + fq * 4;
#pragma unroll
        for (int ni = 0; ni < 2; ++ni) {
            const int gc = col0 + wn + ni * 16 + fr;
#pragma unroll
            for (int r = 0; r < 4; ++r) {
                const size_t o = ob + (size_t)(gr + r) * NC + gc;
                Out[o] = X[o] + acc[mi][ni][r];
            }
        }
    }
}

extern "C" void kernel_launch(void* const* d_in, const int* in_sizes, int n_in,
                              void* d_out, int out_size, void* d_ws, size_t ws_size,
                              hipStream_t stream)
{
    const float* X  = (const float*)d_in[0];
    const float* Wx = (const float*)d_in[1];
    const float* bx = (const float*)d_in[2];
    const float* Wy = (const float*)d_in[3];
    const float* by = (const float*)d_in[4];
    const float* Wo = (const float*)d_in[5];
    const float* bo = (const float*)d_in[6];
    float* out = (float*)d_out;

    // Workspace (~97 MB): S16 [0,64MB); Xf16 (16MB) overlaps S16[0:16MB) — dead
    // (proj done) before score_kernel writes S16 (stream-ordered).
    char* ws = (char*)d_ws;
    u16* S16 = (u16*)ws;
    u16* Xf  = (u16*)ws;
    char* p = ws + 67108864;
    u16* xp  = (u16*)p; p += 8388608;
    u16* yp  = (u16*)p; p += 8388608;
    u16* opT = (u16*)p; p += 16777216;
    u16* WxT = (u16*)p; p += 262144;
    u16* WyT = (u16*)p; p += 262144;
    u16* WoT = (u16*)p; p += 524288;

    cvt_x_kernel<<<4096, 256, 0, stream>>>(X, Xf);
    cvt_w_kernel<<<1024, 256, 0, stream>>>(Wx, Wy, Wo, WxT, WyT, WoT);
    proj_kernel<<<dim3(128, 8), 256, 0, stream>>>(Xf, WxT, WyT, WoT, bx, by, bo, xp, yp, opT);
    score_kernel<<<dim3(16, 16, NB), 256, 0, stream>>>(xp, yp, S16);
    softmax_kernel<<<2048, 256, 0, stream>>>(S16);
    out_kernel<<<dim3(16, 4, NB), 512, 0, stream>>>(S16, opT, X, out);
}

// Round 6
// 216.819 us; speedup vs baseline: 5.2331x; 1.0139x over previous
//
#include <hip/hip_runtime.h>

// NonLocalBlock B=8, L=2048, C=512, CI=256 (fp32 in/out).
// Round 6:
//   - score_softmax FUSED: each block computes one 64x64 (l,m) tile for ALL
//     8 batches (K=256 GEMM per b); each thread then owns all 8 b values of
//     its 16 C/D slots -> register-only batch softmax -> writes attn fp16.
//     Kills the softmax kernel + the 128 MB S16 write/read round trip.
//   - out_kernel: issue-early LDS double-buffer, ONE barrier per K-iter:
//     barrier -> issue next-tile global_load_lds (other buffer) -> compute.
//     Loads fly during compute (was: serial stage/drain/compute).
//   All-fp16, XOR k-chunk swizzle (0 bank conflicts).

#define NB 8
#define NL 2048
#define NC 512
#define NCI 256

using f16x8 = __attribute__((ext_vector_type(8))) _Float16;
using f32x4 = __attribute__((ext_vector_type(4))) float;
typedef unsigned short u16;

__device__ __forceinline__ u16 f16b(float x) {
    _Float16 h = (_Float16)x;
    return __builtin_bit_cast(u16, h);
}
__device__ __forceinline__ float f16tof(u16 u) {
    return (float)__builtin_bit_cast(_Float16, u);
}
__device__ __forceinline__ void gload16(const void* g, void* l) {
    __builtin_amdgcn_global_load_lds((__attribute__((address_space(1))) void*)g,
                                     (__attribute__((address_space(3))) void*)l,
                                     16, 0, 0);
}

// ---- cvt: X fp32 -> fp16 --------------------------------------------------
__global__ __launch_bounds__(256) void cvt_x_kernel(const float* __restrict__ X,
                                                    u16* __restrict__ Xf)
{
    size_t i = (size_t)blockIdx.x * 256 + threadIdx.x;   // per 8 elements
    const float4* X4 = (const float4*)X;
    float4 a = X4[2 * i], b = X4[2 * i + 1];
    u16 o[8] = {f16b(a.x), f16b(a.y), f16b(a.z), f16b(a.w),
                f16b(b.x), f16b(b.y), f16b(b.z), f16b(b.w)};
    ((uint4*)Xf)[i] = *(const uint4*)o;
}

// ---- cvt: transpose weights to [n][k] fp16 --------------------------------
__global__ __launch_bounds__(256) void cvt_w_kernel(
    const float* __restrict__ Wx, const float* __restrict__ Wy, const float* __restrict__ Wo,
    u16* __restrict__ WxT, u16* __restrict__ WyT, u16* __restrict__ WoT)
{
    const int bid = blockIdx.x, t = threadIdx.x;
#pragma unroll
    for (int kk = 0; kk < 2; ++kk) {
        const int k = t + kk * 256;
        if (bid < 256)      WxT[(size_t)bid * NC + k] = f16b(Wx[(size_t)k * NCI + bid]);
        else if (bid < 512) WyT[(size_t)(bid - 256) * NC + k] = f16b(Wy[(size_t)k * NCI + (bid - 256)]);
        else                WoT[(size_t)(bid - 512) * NC + k] = f16b(Wo[(size_t)k * NC + (bid - 512)]);
    }
}

// ---- projections: grid (128, 8); cb 0-1 xp, 2-3 yp, 4-7 op (transposed) ----
__global__ __launch_bounds__(256) void proj_kernel(
    const u16* __restrict__ Xf,
    const u16* __restrict__ WxT, const u16* __restrict__ WyT, const u16* __restrict__ WoT,
    const float* __restrict__ bx, const float* __restrict__ by, const float* __restrict__ bo,
    u16* __restrict__ xp, u16* __restrict__ yp, u16* __restrict__ opT)
{
    __shared__ __align__(16) u16 SM[17408];   // As 8192 + Bs 8192; Ts reuse 128x136
    u16* As = SM;
    u16* Bs = SM + 8192;

    const int tid = threadIdx.x;
    const int w = tid >> 6, lane = tid & 63;
    const int row0 = blockIdx.x * 128;
    const int cb = blockIdx.y;

    const u16* W; const float* bias; int n0, path;
    if (cb < 2)      { path = 0; n0 = cb * 128;       W = WxT; bias = bx; }
    else if (cb < 4) { path = 1; n0 = (cb - 2) * 128; W = WyT; bias = by; }
    else             { path = 2; n0 = (cb - 4) * 128; W = WoT; bias = bo; }

    f32x4 acc[4][4] = {};
    const int wm = (w & 1) * 64, wn = (w >> 1) * 64;
    const int fr = lane & 15, fq = lane >> 4;

    for (int k0 = 0; k0 < NC; k0 += 64) {
#pragma unroll
        for (int pass = 0; pass < 4; ++pass) {
            const int cbase = pass * 256 + w * 64;   // wave-uniform
            const int chunk = cbase + lane;
            const int r = chunk >> 3;
            const int kc = (chunk & 7) ^ (r & 7);    // XOR-swizzled k-chunk
            gload16(Xf + (size_t)(row0 + r) * NC + k0 + kc * 8, (char*)As + cbase * 16);
            gload16(W  + (size_t)(n0  + r) * NC + k0 + kc * 8, (char*)Bs + cbase * 16);
        }
        __syncthreads();
        f16x8 a[4][2], b[4][2];
#pragma unroll
        for (int mi = 0; mi < 4; ++mi)
#pragma unroll
            for (int kt = 0; kt < 2; ++kt)
                a[mi][kt] = *(const f16x8*)&As[(wm + mi * 16 + fr) * 64 + ((kt * 4 + fq) ^ (fr & 7)) * 8];
#pragma unroll
        for (int ni = 0; ni < 4; ++ni)
#pragma unroll
            for (int kt = 0; kt < 2; ++kt)
                b[ni][kt] = *(const f16x8*)&Bs[(wn + ni * 16 + fr) * 64 + ((kt * 4 + fq) ^ (fr & 7)) * 8];
#pragma unroll
        for (int kt = 0; kt < 2; ++kt)
#pragma unroll
            for (int mi = 0; mi < 4; ++mi)
#pragma unroll
                for (int ni = 0; ni < 4; ++ni)
                    acc[mi][ni] = __builtin_amdgcn_mfma_f32_16x16x32_f16(a[mi][kt], b[ni][kt], acc[mi][ni], 0, 0, 0);
        __syncthreads();
    }

    if (path != 2) {
        u16* O = (path == 0) ? xp : yp;
#pragma unroll
        for (int mi = 0; mi < 4; ++mi) {
            const int grow = row0 + wm + mi * 16 + fq * 4;
#pragma unroll
            for (int ni = 0; ni < 4; ++ni) {
                const int gcol = n0 + wn + ni * 16 + fr;
                const float bv = bias[gcol];
#pragma unroll
                for (int r = 0; r < 4; ++r)
                    O[(size_t)(grow + r) * NCI + gcol] = f16b(acc[mi][ni][r] + bv);
            }
        }
    } else {
        u16* Ts = SM;   // 128 x 136 fp16 transpose staging
#pragma unroll
        for (int mi = 0; mi < 4; ++mi) {
            const int mb = wm + mi * 16 + fq * 4;
#pragma unroll
            for (int ni = 0; ni < 4; ++ni) {
                const int nl_ = wn + ni * 16 + fr;
                const float bv = bias[n0 + nl_];
#pragma unroll
                for (int r = 0; r < 4; ++r)
                    Ts[nl_ * 136 + mb + r] = f16b(acc[mi][ni][r] + bv);
            }
        }
        __syncthreads();
        const int b = row0 >> 11, m0 = row0 & 2047;
        u16* dst = opT + (size_t)b * NC * NL + (size_t)n0 * NL + m0;
        for (int i = tid; i < 128 * 16; i += 256) {
            const int c = i >> 4, ch = i & 15;
            uint4 v = *(const uint4*)&Ts[c * 136 + ch * 8];
            *(uint4*)&dst[(size_t)c * NL + ch * 8] = v;
        }
    }
}

// ---- FUSED score+softmax --------------------------------------------------
// Grid (32,32), 256 thr / 4 waves. Block = one 64x64 (l,m) tile, ALL 8 b.
// Wave tile 64(m) x 16(n). Per thread: 16 C/D slots x 8 b packed in 64 VGPRs.
__global__ __launch_bounds__(256) void score_softmax_kernel(
    const u16* __restrict__ xp, const u16* __restrict__ yp, u16* __restrict__ ATT)
{
    __shared__ __align__(16) u16 As[4096], Bs[4096];   // 64 x 64 each (8 KB)
    const int tid = threadIdx.x;
    const int w = tid >> 6, lane = tid & 63;
    const int row0 = blockIdx.x * 64, col0 = blockIdx.y * 64;
    const int wn = w * 16;
    const int fr = lane & 15, fq = lane >> 4;

    unsigned sv[NB][8];   // [b][mi*2+rp]: lo half r=rp*2, hi half r=rp*2+1

#pragma unroll
    for (int b = 0; b < NB; ++b) {
        const u16* A = xp + (size_t)b * NL * NCI;
        const u16* B = yp + (size_t)b * NL * NCI;
        f32x4 acc[4] = {};
        for (int k0 = 0; k0 < NCI; k0 += 64) {
#pragma unroll
            for (int pass = 0; pass < 2; ++pass) {
                const int cbase = pass * 256 + w * 64;   // wave-uniform
                const int chunk = cbase + lane;
                const int r = chunk >> 3;
                const int kc = (chunk & 7) ^ (r & 7);
                gload16(A + (size_t)(row0 + r) * NCI + k0 + kc * 8, (char*)As + cbase * 16);
                gload16(B + (size_t)(col0 + r) * NCI + k0 + kc * 8, (char*)Bs + cbase * 16);
            }
            __syncthreads();
            f16x8 af[4][2], bf[2];
#pragma unroll
            for (int mi = 0; mi < 4; ++mi)
#pragma unroll
                for (int kt = 0; kt < 2; ++kt)
                    af[mi][kt] = *(const f16x8*)&As[(mi * 16 + fr) * 64 + ((kt * 4 + fq) ^ (fr & 7)) * 8];
#pragma unroll
            for (int kt = 0; kt < 2; ++kt)
                bf[kt] = *(const f16x8*)&Bs[(wn + fr) * 64 + ((kt * 4 + fq) ^ (fr & 7)) * 8];
#pragma unroll
            for (int kt = 0; kt < 2; ++kt)
#pragma unroll
                for (int mi = 0; mi < 4; ++mi)
                    acc[mi] = __builtin_amdgcn_mfma_f32_16x16x32_f16(af[mi][kt], bf[kt], acc[mi], 0, 0, 0);
            __syncthreads();
        }
#pragma unroll
        for (int mi = 0; mi < 4; ++mi) {
            sv[b][mi * 2 + 0] = (unsigned)f16b(acc[mi][0]) | ((unsigned)f16b(acc[mi][1]) << 16);
            sv[b][mi * 2 + 1] = (unsigned)f16b(acc[mi][2]) | ((unsigned)f16b(acc[mi][3]) << 16);
        }
    }

    // register-only softmax over b, then write attn fp16
    const int gc = col0 + wn + fr;
#pragma unroll
    for (int mi = 0; mi < 4; ++mi) {
#pragma unroll
        for (int rp = 0; rp < 2; ++rp) {
            float v0[NB], v1[NB];
#pragma unroll
            for (int b = 0; b < NB; ++b) {
                unsigned u = sv[b][mi * 2 + rp];
                v0[b] = f16tof((u16)(u & 0xFFFF));
                v1[b] = f16tof((u16)(u >> 16));
            }
            float m0 = v0[0], m1 = v1[0];
#pragma unroll
            for (int b = 1; b < NB; ++b) { m0 = fmaxf(m0, v0[b]); m1 = fmaxf(m1, v1[b]); }
            float s0 = 0.f, s1 = 0.f;
#pragma unroll
            for (int b = 0; b < NB; ++b) {
                v0[b] = __expf(v0[b] - m0); s0 += v0[b];
                v1[b] = __expf(v1[b] - m1); s1 += v1[b];
            }
            const float i0 = 1.f / s0, i1 = 1.f / s1;
            const int gr0 = row0 + mi * 16 + fq * 4 + rp * 2;
#pragma unroll
            for (int b = 0; b < NB; ++b) {
                u16* dst = ATT + (size_t)b * NL * NL;
                dst[(size_t)gr0 * NL + gc]       = f16b(v0[b] * i0);
                dst[(size_t)(gr0 + 1) * NL + gc] = f16b(v1[b] * i1);
            }
        }
    }
}

// ---- out: out[b] = X[b] + attn[b] @ op[b], 512 thr, issue-early dbuf -------
__global__ __launch_bounds__(512) void out_kernel(
    const u16* __restrict__ ATT, const u16* __restrict__ opT,
    const float* __restrict__ X, float* __restrict__ Out)
{
    __shared__ __align__(16) u16 As[2][8192], Bs[2][8192];   // 128 x 64 each, x2
    const int tid = threadIdx.x;
    const int w = tid >> 6, lane = tid & 63;
    const int b = blockIdx.z;
    const int row0 = blockIdx.x * 128, col0 = blockIdx.y * 128;
    const u16* Aatt = ATT + (size_t)b * NL * NL;
    const u16* Bsrc = opT + (size_t)b * NC * NL;

    f32x4 acc[4][2] = {};
    const int wm = (w & 1) * 64, wn = (w >> 1) * 32;
    const int fr = lane & 15, fq = lane >> 4;

    // staging helper (as lambda): stage K-chunk k0 into buffer bu
    auto stage = [&](int k0, int bu) {
#pragma unroll
        for (int pass = 0; pass < 2; ++pass) {
            const int cbase = pass * 512 + w * 64;   // wave-uniform
            const int chunk = cbase + lane;
            const int r = chunk >> 3;
            const int kc = (chunk & 7) ^ (r & 7);
            gload16(Aatt + (size_t)(row0 + r) * NL + k0 + kc * 8, (char*)&As[bu][0] + cbase * 16);
            gload16(Bsrc + (size_t)(col0 + r) * NL + k0 + kc * 8, (char*)&Bs[bu][0] + cbase * 16);
        }
    };

    stage(0, 0);
    int bu = 0;
    for (int it = 0; it < NL / 64; ++it) {
        __syncthreads();                         // own vmcnt(0) drained -> buf[bu] ready
        if (it + 1 < NL / 64) stage((it + 1) * 64, bu ^ 1);   // issue early, fly during compute
        f16x8 af[4][2], bf[2][2];
#pragma unroll
        for (int mi = 0; mi < 4; ++mi)
#pragma unroll
            for (int kt = 0; kt < 2; ++kt)
                af[mi][kt] = *(const f16x8*)&As[bu][(wm + mi * 16 + fr) * 64 + ((kt * 4 + fq) ^ (fr & 7)) * 8];
#pragma unroll
        for (int ni = 0; ni < 2; ++ni)
#pragma unroll
            for (int kt = 0; kt < 2; ++kt)
                bf[ni][kt] = *(const f16x8*)&Bs[bu][(wn + ni * 16 + fr) * 64 + ((kt * 4 + fq) ^ (fr & 7)) * 8];
#pragma unroll
        for (int kt = 0; kt < 2; ++kt)
#pragma unroll
            for (int mi = 0; mi < 4; ++mi)
#pragma unroll
                for (int ni = 0; ni < 2; ++ni)
                    acc[mi][ni] = __builtin_amdgcn_mfma_f32_16x16x32_f16(af[mi][kt], bf[ni][kt], acc[mi][ni], 0, 0, 0);
        bu ^= 1;
    }
    const size_t ob = (size_t)b * NL * NC;
#pragma unroll
    for (int mi = 0; mi < 4; ++mi) {
        const int gr = row0 + wm + mi * 16 + fq * 4;
#pragma unroll
        for (int ni = 0; ni < 2; ++ni) {
            const int gc = col0 + wn + ni * 16 + fr;
#pragma unroll
            for (int r = 0; r < 4; ++r) {
                const size_t o = ob + (size_t)(gr + r) * NC + gc;
                Out[o] = X[o] + acc[mi][ni][r];
            }
        }
    }
}

extern "C" void kernel_launch(void* const* d_in, const int* in_sizes, int n_in,
                              void* d_out, int out_size, void* d_ws, size_t ws_size,
                              hipStream_t stream)
{
    const float* X  = (const float*)d_in[0];
    const float* Wx = (const float*)d_in[1];
    const float* bx = (const float*)d_in[2];
    const float* Wy = (const float*)d_in[3];
    const float* by = (const float*)d_in[4];
    const float* Wo = (const float*)d_in[5];
    const float* bo = (const float*)d_in[6];
    float* out = (float*)d_out;

    // Workspace (~97 MB): ATT fp16 [0,64MB); Xf16 (16MB) overlaps ATT[0:16MB) —
    // dead (proj done) before score_softmax writes ATT (stream-ordered).
    char* ws = (char*)d_ws;
    u16* ATT = (u16*)ws;
    u16* Xf  = (u16*)ws;
    char* p = ws + 67108864;
    u16* xp  = (u16*)p; p += 8388608;
    u16* yp  = (u16*)p; p += 8388608;
    u16* opT = (u16*)p; p += 16777216;
    u16* WxT = (u16*)p; p += 262144;
    u16* WyT = (u16*)p; p += 262144;
    u16* WoT = (u16*)p; p += 524288;

    cvt_x_kernel<<<4096, 256, 0, stream>>>(X, Xf);
    cvt_w_kernel<<<1024, 256, 0, stream>>>(Wx, Wy, Wo, WxT, WyT, WoT);
    proj_kernel<<<dim3(128, 8), 256, 0, stream>>>(Xf, WxT, WyT, WoT, bx, by, bo, xp, yp, opT);
    score_softmax_kernel<<<dim3(32, 32), 256, 0, stream>>>(xp, yp, ATT);
    out_kernel<<<dim3(16, 4, NB), 512, 0, stream>>>(ATT, opT, X, out);
}